// Round 8
// baseline (1441.420 us; speedup 1.0000x reference)
//
#include <hip/hip_runtime.h>

typedef __attribute__((ext_vector_type(8))) short bf16x8;
typedef __attribute__((ext_vector_type(4))) float f32x4;

#define FP const float* __restrict__

__device__ __forceinline__ short f2bf(float f) {
    unsigned u = __float_as_uint(f);
    u += 0x7fffu + ((u >> 16) & 1u);
    return (short)(u >> 16);
}
__device__ __forceinline__ float bf2f(short s) {
    return __uint_as_float(((unsigned)(unsigned short)s) << 16);
}
__device__ __forceinline__ float v_exp2(float x) { float r; asm("v_exp_f32 %0, %1" : "=v"(r) : "v"(x)); return r; }
__device__ __forceinline__ float v_log2(float x) { float r; asm("v_log_f32 %0, %1" : "=v"(r) : "v"(x)); return r; }

__device__ __forceinline__ float fexp(float x) { return v_exp2(1.44269504f * x); }
__device__ __forceinline__ float sp(float x) {         // softplus, branch-free
    return fmaxf(x, 0.f) + 0.69314718f * v_log2(1.f + v_exp2(-1.44269504f * fabsf(x)));
}
__device__ __forceinline__ float silu_f(float x) {
    return x * __builtin_amdgcn_rcpf(1.f + v_exp2(-1.44269504f * x));
}

// A-operand = W^T tile: lane l holds W[k, c0+(l&15)], k = 8*(l>>4)+j. W is [32+,ld] f32.
__device__ __forceinline__ bf16x8 load_wfrag(FP w, int ld, int c0, int l) {
    const int c = c0 + (l & 15);
    const int k0 = 8 * (l >> 4);
    bf16x8 f;
#pragma unroll
    for (int j = 0; j < 8; ++j) f[j] = f2bf(w[(k0 + j) * ld + c]);
    return f;
}

// ---------------------------------------------------------------------------
// kprep: bf16-ize atom (N*32) and ef (E*32)
// ---------------------------------------------------------------------------
__global__ __launch_bounds__(256) void kprep(
    FP atom, FP ef, short* __restrict__ atomb, short* __restrict__ efb,
    int nA4, int nE4)
{
    const int stride = gridDim.x * 256;
    for (int t = blockIdx.x * 256 + threadIdx.x; t < nA4 + nE4; t += stride) {
        float4 v;
        short4 s;
        if (t < nA4) {
            v = ((const float4*)atom)[t];
            s.x = f2bf(v.x); s.y = f2bf(v.y); s.z = f2bf(v.z); s.w = f2bf(v.w);
            ((short4*)atomb)[t] = s;
        } else {
            v = ((const float4*)ef)[t - nA4];
            s.x = f2bf(v.x); s.y = f2bf(v.y); s.z = f2bf(v.z); s.w = f2bf(v.w);
            ((short4*)efb)[t - nA4] = s;
        }
    }
}

// ---------------------------------------------------------------------------
// kgath: PURE gather, max TLP. chunk t: e=t>>3, s=(t>>2)&1, c=t&3
//   gx[e*64 + s*32 + c*8 .. +8] = atomb[eidx[e + s*E]*32 + c*8 .. +8]
// 4 consecutive lanes cover one 64B row -> 16 line-requests/wave-instr.
// ---------------------------------------------------------------------------
__global__ __launch_bounds__(256) void kgath(
    const int* __restrict__ eidx, const short* __restrict__ atomb,
    short* __restrict__ gx, int E)
{
    const int stride = gridDim.x * 256;
    const int tot = 8 * E;
    for (int t = blockIdx.x * 256 + threadIdx.x; t < tot; t += stride) {
        const int e = t >> 3, s = (t >> 2) & 1, c = t & 3;
        const int node = eidx[e + (s ? E : 0)];
        const float4 v = *(const float4*)&atomb[(size_t)node * 32 + c * 8];
        *(float4*)&gx[(size_t)t * 8] = v;
    }
}

// ---------------------------------------------------------------------------
// kBc: FULLY STREAMING: reads gx (pre-gathered xi/xj) + efb sequentially.
//   Ee = ef@We, Ha = xi@Wa, Hb = xj@Wa (24 MFMAs); att dot -> alpha0; BN stats.
// No eidx, no gathers.
// ---------------------------------------------------------------------------
__global__ __launch_bounds__(256) void kBc(
    const short* __restrict__ efb, const short* __restrict__ gx,
    FP Wg, FP attg,
    float* __restrict__ alpha, float* __restrict__ bnstat, int E)
{
    __shared__ float attl[256];
    const int t = threadIdx.x;
    if (t < 64) ((float4*)attl)[t] = ((const float4*)attg)[t];
    __syncthreads();

    const int l = t & 63, q = l >> 4, e15 = l & 15;
    const int wv = blockIdx.x * 4 + (t >> 6), nw = gridDim.x * 4;
    bf16x8 wfa[8], wfe[8];
#pragma unroll
    for (int mb = 0; mb < 8; ++mb) {
        wfa[mb] = load_wfrag(Wg, 128, 16 * mb, l);            // rows 0..31 (atom)
        wfe[mb] = load_wfrag(Wg + 32 * 128, 128, 16 * mb, l); // rows 32..63 (edge)
    }
    const f32x4 z = {0.f, 0.f, 0.f, 0.f};
    float bs[4] = {0,0,0,0}, bq2[4] = {0,0,0,0};

    const int nt = E >> 4;
    for (int tt = wv; tt < nt; tt += nw) {
        const int tb = tt * 16;
        const int e = tb + e15;
        const bf16x8 xi = *(const bf16x8*)&gx[(size_t)e * 64 + 8 * q];
        const bf16x8 xj = *(const bf16x8*)&gx[(size_t)e * 64 + 32 + 8 * q];
        const bf16x8 xe = *(const bf16x8*)&efb[(size_t)e * 32 + 8 * q];

        float ph[4] = {0,0,0,0};
#pragma unroll
        for (int mb = 0; mb < 8; ++mb) {
            const f32x4 ee = __builtin_amdgcn_mfma_f32_16x16x32_bf16(wfe[mb], xe, z, 0, 0, 0);
            const f32x4 ha = __builtin_amdgcn_mfma_f32_16x16x32_bf16(wfa[mb], xi, z, 0, 0, 0);
            const f32x4 hb = __builtin_amdgcn_mfma_f32_16x16x32_bf16(wfa[mb], xj, z, 0, 0, 0);
            const int h = mb >> 1;
            const int c0 = (mb & 1) * 16 + 4 * q;
#pragma unroll
            for (int r = 0; r < 4; ++r) {
                ph[h] += sp(ha[r] + ee[r]) * attl[h * 64 + c0 + r]
                       + sp(hb[r] + ee[r]) * attl[h * 64 + 32 + c0 + r];
            }
        }
        float4 a0v;
#pragma unroll
        for (int h = 0; h < 4; ++h) {
            float v = ph[h];
            v += __shfl_xor(v, 16);
            v += __shfl_xor(v, 32);
            (&a0v.x)[h] = sp(v);
        }
        if (q == 0) {
            *(float4*)&alpha[(size_t)e * 4] = a0v;
#pragma unroll
            for (int h = 0; h < 4; ++h) {
                const float a0 = (&a0v.x)[h];
                bs[h] += a0; bq2[h] += a0 * a0;
            }
        }
    }
#pragma unroll
    for (int h = 0; h < 4; ++h) {
        float v = bs[h], w = bq2[h];
#pragma unroll
        for (int d = 1; d < 64; d <<= 1) { v += __shfl_xor(v, d); w += __shfl_xor(w, d); }
        if (l == 0) { atomicAdd(&bnstat[h], v); atomicAdd(&bnstat[4 + h], w); }
    }
}

// k2: finalize BN scale/shift
__global__ void k2_bn(const float* __restrict__ bnstat, FP gam, FP bet,
                      float* __restrict__ bnsc, int E)
{
    const int t = threadIdx.x;
    if (t < 4) {
        const float inv = 1.f / (float)E;
        const float mu  = bnstat[t] * inv;
        const float var = bnstat[4 + t] * inv - mu * mu;
        const float scl = gam[t] * rsqrtf(var + 1e-5f);
        bnsc[t] = scl;
        bnsc[4 + t] = bet[t] - mu * scl;
    }
}

// k3: alpha1 = sp(scale*alpha0+shift); segment max via uint atomicMax (alpha1>0)
__global__ __launch_bounds__(256) void k3_bnmax(
    float* __restrict__ alpha, const int* __restrict__ eidx,
    unsigned int* __restrict__ mbuf, const float* __restrict__ bnsc, int E)
{
    const int t = blockIdx.x * 256 + threadIdx.x;
    if (t >= 4 * E) return;
    const int e = t >> 2, h = t & 3;
    const float a1 = sp(bnsc[h] * alpha[t] + bnsc[4 + h]);
    alpha[t] = a1;
    atomicMax(&mbuf[eidx[e] * 4 + h], __float_as_uint(a1));
}

// k4: ex = exp(alpha1 - m[row]); segment sum
__global__ __launch_bounds__(256) void k4_exps(
    float* __restrict__ alpha, const int* __restrict__ eidx,
    const float* __restrict__ mbuf, float* __restrict__ sbuf, int E)
{
    const int t = blockIdx.x * 256 + threadIdx.x;
    if (t >= 4 * E) return;
    const int e = t >> 2, h = t & 3;
    const float ex = fexp(alpha[t] - mbuf[eidx[e] * 4 + h]);
    alpha[t] = ex;
    atomicAdd(&sbuf[eidx[e] * 4 + h], ex);
}

// ---------------------------------------------------------------------------
// kmsg2: recompute Ee + Hb from STREAMED gx/efb (16 MFMAs); hj = sp(Hb+Ee);
//        out[i] += 0.25*sum_h af_h * hj[h,:]
// ---------------------------------------------------------------------------
__global__ __launch_bounds__(256) void kmsg2(
    const short* __restrict__ efb, const short* __restrict__ gx,
    const int* __restrict__ eidx, FP Wg,
    const float* __restrict__ alpha, const float* __restrict__ sbuf,
    float* __restrict__ outacc, int E)
{
    const int l = threadIdx.x & 63, q = l >> 4, e15 = l & 15;
    const int wv = blockIdx.x * 4 + (threadIdx.x >> 6), nw = gridDim.x * 4;
    bf16x8 wfa[8], wfe[8];
#pragma unroll
    for (int mb = 0; mb < 8; ++mb) {
        wfa[mb] = load_wfrag(Wg, 128, 16 * mb, l);
        wfe[mb] = load_wfrag(Wg + 32 * 128, 128, 16 * mb, l);
    }
    const f32x4 z = {0.f, 0.f, 0.f, 0.f};

    const int nt = E >> 4;
    for (int tt = wv; tt < nt; tt += nw) {
        const int tb = tt * 16;
        const int e = tb + e15;
        const int i = eidx[e];
        const bf16x8 xj = *(const bf16x8*)&gx[(size_t)e * 64 + 32 + 8 * q];
        const bf16x8 xe = *(const bf16x8*)&efb[(size_t)e * 32 + 8 * q];
        const float4 a4 = *(const float4*)&alpha[(size_t)e * 4];
        const float4 s4 = *(const float4*)&sbuf[(size_t)i * 4];
        float af[4];
#pragma unroll
        for (int h = 0; h < 4; ++h)
            af[h] = (&a4.x)[h] * __builtin_amdgcn_rcpf((&s4.x)[h] + 1e-16f);

        float c4[8] = {0,0,0,0,0,0,0,0};
#pragma unroll
        for (int mb = 0; mb < 8; ++mb) {
            const f32x4 ee = __builtin_amdgcn_mfma_f32_16x16x32_bf16(wfe[mb], xe, z, 0, 0, 0);
            const f32x4 hb = __builtin_amdgcn_mfma_f32_16x16x32_bf16(wfa[mb], xj, z, 0, 0, 0);
            const float a = af[mb >> 1];
            const int s = (mb & 1) * 4;
#pragma unroll
            for (int r = 0; r < 4; ++r)
                c4[s + r] += sp(hb[r] + ee[r]) * a;
        }
#pragma unroll
        for (int s2 = 0; s2 < 2; ++s2)
#pragma unroll
            for (int r = 0; r < 4; ++r)
                atomicAdd(&outacc[(size_t)i * 32 + s2 * 16 + 4 * q + r], 0.25f * c4[s2 * 4 + r]);
    }
}

// kout: out += bias; also write bf16 copy for the edge-MLP gathers
__global__ __launch_bounds__(256) void kout(
    float* __restrict__ outp, FP bias, short* __restrict__ outb, int N)
{
    const int t = blockIdx.x * 256 + threadIdx.x;
    if (t < N * 32) {
        const float v = outp[t] + bias[t & 31];
        outp[t] = v;
        outb[t] = f2bf(v);
    }
}

// ---------------------------------------------------------------------------
// kG2v: edge MLP. x = [outb[row] | outb[col] | efb] (K=96, 3 MFMA k-steps,
// W1 frags in LDS); h = silu(.+b1) -> LDS bounce -> eout = silu(h@W2+b2).
// ---------------------------------------------------------------------------
__global__ __launch_bounds__(256) void kG2v(
    const short* __restrict__ efb, const int* __restrict__ eidx,
    const short* __restrict__ outb,
    FP W1g, FP W2, FP b1g, FP b2g, float* __restrict__ eout, int E)
{
    __shared__ __align__(16) short W1f[3][8][64][8];   // 24 KB, frag layout
    __shared__ float b1l[128];
    __shared__ float b2l[32];
    __shared__ __align__(16) short hs[4][16 * 132];    // 16.9 KB h-bounce
    const int t = threadIdx.x;
    for (int s = t; s < 3 * 8 * 64; s += 256) {
        const int ks = s >> 9, rem = s & 511, mb = rem >> 6, ll = rem & 63;
        const int c = 16 * mb + (ll & 15);
        const int k0 = ks * 32 + 8 * (ll >> 4);
        bf16x8 f;
#pragma unroll
        for (int j = 0; j < 8; ++j) f[j] = f2bf(W1g[(size_t)(k0 + j) * 128 + c]);
        *(bf16x8*)&W1f[ks][mb][ll][0] = f;
    }
    if (t < 128) b1l[t] = b1g[t];
    if (t < 32)  b2l[t] = b2g[t];
    __syncthreads();

    const int l = t & 63, q = l >> 4, e15 = l & 15, wvb = t >> 6;
    short* hw = &hs[wvb][0];
    bf16x8 w2f[4][2];
#pragma unroll
    for (int kc = 0; kc < 4; ++kc)
#pragma unroll
        for (int m2 = 0; m2 < 2; ++m2)
            w2f[kc][m2] = load_wfrag(W2 + 32 * kc * 32, 32, 16 * m2, l);
    const f32x4 z = {0.f, 0.f, 0.f, 0.f};

    const int wv = blockIdx.x * 4 + wvb, nw = gridDim.x * 4, nt = E >> 4;
    for (int tt = wv; tt < nt; tt += nw) {
        const int tb = tt * 16;
        const int e = tb + e15;
        const int ri = eidx[e], ci = eidx[E + e];
        bf16x8 xb[3];
        xb[0] = *(const bf16x8*)&outb[(size_t)ri * 32 + 8 * q];
        xb[1] = *(const bf16x8*)&outb[(size_t)ci * 32 + 8 * q];
        xb[2] = *(const bf16x8*)&efb[(size_t)e * 32 + 8 * q];

        f32x4 a1[8] = {z, z, z, z, z, z, z, z};
#pragma unroll
        for (int ks = 0; ks < 3; ++ks)
#pragma unroll
            for (int mb = 0; mb < 8; ++mb) {
                const bf16x8 wfr = *(const bf16x8*)&W1f[ks][mb][l][0];
                a1[mb] = __builtin_amdgcn_mfma_f32_16x16x32_bf16(wfr, xb[ks], a1[mb], 0, 0, 0);
            }
        // silu + bounce into B-frag layout
#pragma unroll
        for (int mb = 0; mb < 8; ++mb) {
            short4 s;
            s.x = f2bf(silu_f(a1[mb][0] + b1l[16 * mb + 4 * q + 0]));
            s.y = f2bf(silu_f(a1[mb][1] + b1l[16 * mb + 4 * q + 1]));
            s.z = f2bf(silu_f(a1[mb][2] + b1l[16 * mb + 4 * q + 2]));
            s.w = f2bf(silu_f(a1[mb][3] + b1l[16 * mb + 4 * q + 3]));
            *(short4*)&hw[e15 * 132 + 16 * mb + 4 * q] = s;
        }
        f32x4 oc0 = z, oc1 = z;
#pragma unroll
        for (int kc = 0; kc < 4; ++kc) {
            const bf16x8 hf = *(const bf16x8*)&hw[e15 * 132 + kc * 32 + 8 * q];
            oc0 = __builtin_amdgcn_mfma_f32_16x16x32_bf16(w2f[kc][0], hf, oc0, 0, 0, 0);
            oc1 = __builtin_amdgcn_mfma_f32_16x16x32_bf16(w2f[kc][1], hf, oc1, 0, 0, 0);
        }
        float4 o0, o1;
#pragma unroll
        for (int r = 0; r < 4; ++r) {
            (&o0.x)[r] = silu_f(oc0[r] + b2l[4 * q + r]);
            (&o1.x)[r] = silu_f(oc1[r] + b2l[16 + 4 * q + r]);
        }
        *(float4*)&eout[(size_t)e * 32 + 4 * q] = o0;
        *(float4*)&eout[(size_t)e * 32 + 16 + 4 * q] = o1;
    }
}

extern "C" void kernel_launch(void* const* d_in, const int* in_sizes, int n_in,
                              void* d_out, int out_size, void* d_ws, size_t ws_size,
                              hipStream_t stream)
{
    const float* atom = (const float*)d_in[0];
    const int*   eidx = (const int*)d_in[1];
    const float* efea = (const float*)d_in[2];
    const float* Wg   = (const float*)d_in[6];
    const float* attg = (const float*)d_in[7];
    const float* bias = (const float*)d_in[8];
    const float* gam  = (const float*)d_in[9];
    const float* bet  = (const float*)d_in[10];
    const float* W1g  = (const float*)d_in[11];
    const float* b1g  = (const float*)d_in[12];
    const float* W2g  = (const float*)d_in[13];
    const float* b2g  = (const float*)d_in[14];

    const int N = in_sizes[0] / 32;
    const int E = in_sizes[2] / 32;

    // workspace layout
    float* ws     = (float*)d_ws;
    float* mbuf   = ws;                               // 4N f32
    float* sbuf   = ws + (size_t)4 * N;               // 4N f32
    float* bnstat = ws + (size_t)8 * N;               // 8
    float* bnsc   = bnstat + 8;                       // 8
    short* atomb  = (short*)(ws + (size_t)8 * N + 16);// N*32 bf16
    short* efb    = atomb + (size_t)N * 32;           // E*32 bf16
    short* outb   = efb + (size_t)E * 32;             // N*32 bf16
    short* gx     = outb + (size_t)N * 32;            // E*64 bf16 (xi|xj rows)

    // d_out: [out N*32 f32][eout E*32 f32]; eout region doubles as alpha scratch
    float* outp  = (float*)d_out;
    float* alpha = outp + (size_t)N * 32;             // 4E f32 (dead before eout write)
    float* eout  = outp + (size_t)N * 32;

    hipMemsetAsync(outp, 0, (size_t)N * 32 * sizeof(float), stream);
    hipMemsetAsync(ws, 0, ((size_t)8 * N + 16) * sizeof(float), stream);

    const int n4e = 4 * E;
    kprep<<<1024, 256, 0, stream>>>(atom, efea, atomb, efb, N * 8, E * 8);
    kgath<<<4096, 256, 0, stream>>>(eidx, atomb, gx, E);
    kBc  <<<2048, 256, 0, stream>>>(efb, gx, Wg, attg, alpha, bnstat, E);
    k2_bn<<<1, 64, 0, stream>>>(bnstat, gam, bet, bnsc, E);
    k3_bnmax<<<(n4e + 255) / 256, 256, 0, stream>>>(alpha, eidx, (unsigned int*)mbuf, bnsc, E);
    k4_exps <<<(n4e + 255) / 256, 256, 0, stream>>>(alpha, eidx, mbuf, sbuf, E);
    kmsg2<<<2048, 256, 0, stream>>>(efb, gx, eidx, Wg, alpha, sbuf, outp, E);
    kout <<<(N * 32 + 255) / 256, 256, 0, stream>>>(outp, bias, outb, N);
    kG2v <<<2048, 256, 0, stream>>>(efb, eidx, outb, W1g, W2g, b1g, b2g, eout, E);
}

// Round 9
// 1438.364 us; speedup vs baseline: 1.0021x; 1.0021x over previous
//
#include <hip/hip_runtime.h>

typedef __attribute__((ext_vector_type(8))) short bf16x8;
typedef __attribute__((ext_vector_type(4))) float f32x4;

#define FP const float* __restrict__

__device__ __forceinline__ short f2bf(float f) {
    unsigned u = __float_as_uint(f);
    u += 0x7fffu + ((u >> 16) & 1u);
    return (short)(u >> 16);
}
__device__ __forceinline__ float bf2f(short s) {
    return __uint_as_float(((unsigned)(unsigned short)s) << 16);
}
__device__ __forceinline__ float v_exp2(float x) { float r; asm("v_exp_f32 %0, %1" : "=v"(r) : "v"(x)); return r; }
__device__ __forceinline__ float v_log2(float x) { float r; asm("v_log_f32 %0, %1" : "=v"(r) : "v"(x)); return r; }

__device__ __forceinline__ float fexp(float x) { return v_exp2(1.44269504f * x); }
__device__ __forceinline__ float sp(float x) {         // softplus, branch-free
    return fmaxf(x, 0.f) + 0.69314718f * v_log2(1.f + v_exp2(-1.44269504f * fabsf(x)));
}
__device__ __forceinline__ float silu_f(float x) {
    return x * __builtin_amdgcn_rcpf(1.f + v_exp2(-1.44269504f * x));
}

// A-operand = W^T tile: lane l holds W[k, c0+(l&15)], k = 8*(l>>4)+j. W is [32+,ld] f32.
__device__ __forceinline__ bf16x8 load_wfrag(FP w, int ld, int c0, int l) {
    const int c = c0 + (l & 15);
    const int k0 = 8 * (l >> 4);
    bf16x8 f;
#pragma unroll
    for (int j = 0; j < 8; ++j) f[j] = f2bf(w[(k0 + j) * ld + c]);
    return f;
}

// ---------------------------------------------------------------------------
// kprep: bf16-ize atom (N*32) and ef (E*32)
// ---------------------------------------------------------------------------
__global__ __launch_bounds__(256) void kprep(
    FP atom, FP ef, short* __restrict__ atomb, short* __restrict__ efb,
    int nA4, int nE4)
{
    const int stride = gridDim.x * 256;
    for (int t = blockIdx.x * 256 + threadIdx.x; t < nA4 + nE4; t += stride) {
        float4 v;
        short4 s;
        if (t < nA4) {
            v = ((const float4*)atom)[t];
            s.x = f2bf(v.x); s.y = f2bf(v.y); s.z = f2bf(v.z); s.w = f2bf(v.w);
            ((short4*)atomb)[t] = s;
        } else {
            v = ((const float4*)ef)[t - nA4];
            s.x = f2bf(v.x); s.y = f2bf(v.y); s.z = f2bf(v.z); s.w = f2bf(v.w);
            ((short4*)efb)[t - nA4] = s;
        }
    }
}

// ---------------------------------------------------------------------------
// kgath: PURE gather, max TLP (measured fast in R8)
// ---------------------------------------------------------------------------
__global__ __launch_bounds__(256) void kgath(
    const int* __restrict__ eidx, const short* __restrict__ atomb,
    short* __restrict__ gx, int E)
{
    const int stride = gridDim.x * 256;
    const int tot = 8 * E;
    for (int t = blockIdx.x * 256 + threadIdx.x; t < tot; t += stride) {
        const int e = t >> 3, s = (t >> 2) & 1, c = t & 3;
        const int node = eidx[e + (s ? E : 0)];
        const float4 v = *(const float4*)&atomb[(size_t)node * 32 + c * 8];
        *(float4*)&gx[(size_t)t * 8] = v;
    }
}

// ---------------------------------------------------------------------------
// kBc: streaming compute. Weight fragments staged in LDS (16 KB) so they are
// NOT rematerialized from global per tile (R8 floor: VGPR=60 forced remat).
// ---------------------------------------------------------------------------
__global__ __launch_bounds__(256, 2) void kBc(
    const short* __restrict__ efb, const short* __restrict__ gx,
    FP Wg, FP attg,
    float* __restrict__ alpha, float* __restrict__ bnstat, int E)
{
    __shared__ float attl[256];
    __shared__ __align__(16) short Wl[16][64][8];   // 16 KB: frag f, lane, 8 bf16
    const int t = threadIdx.x;
    if (t < 64) ((float4*)attl)[t] = ((const float4*)attg)[t];
    for (int s = t; s < 1024; s += 256) {
        const int f = s >> 6, ll = s & 63;
        FP src = (f < 8) ? Wg : (Wg + 32 * 128);
        bf16x8 fr = load_wfrag(src, 128, 16 * (f & 7), ll);
        *(bf16x8*)&Wl[f][ll][0] = fr;
    }
    __syncthreads();

    const int l = t & 63, q = l >> 4, e15 = l & 15;
    const int wv = blockIdx.x * 4 + (t >> 6), nw = gridDim.x * 4;
    const f32x4 z = {0.f, 0.f, 0.f, 0.f};
    float bs[4] = {0,0,0,0}, bq2[4] = {0,0,0,0};

    const int nt = E >> 4;
    for (int tt = wv; tt < nt; tt += nw) {
        const int tb = tt * 16;
        const int e = tb + e15;
        const bf16x8 xi = *(const bf16x8*)&gx[(size_t)e * 64 + 8 * q];
        const bf16x8 xj = *(const bf16x8*)&gx[(size_t)e * 64 + 32 + 8 * q];
        const bf16x8 xe = *(const bf16x8*)&efb[(size_t)e * 32 + 8 * q];

        float ph[4] = {0,0,0,0};
#pragma unroll
        for (int mb = 0; mb < 8; ++mb) {
            const bf16x8 wa = *(const bf16x8*)&Wl[mb][l][0];
            const bf16x8 we = *(const bf16x8*)&Wl[8 + mb][l][0];
            const f32x4 ee = __builtin_amdgcn_mfma_f32_16x16x32_bf16(we, xe, z, 0, 0, 0);
            const f32x4 ha = __builtin_amdgcn_mfma_f32_16x16x32_bf16(wa, xi, z, 0, 0, 0);
            const f32x4 hb = __builtin_amdgcn_mfma_f32_16x16x32_bf16(wa, xj, z, 0, 0, 0);
            const int h = mb >> 1;
            const int c0 = (mb & 1) * 16 + 4 * q;
#pragma unroll
            for (int r = 0; r < 4; ++r) {
                ph[h] += sp(ha[r] + ee[r]) * attl[h * 64 + c0 + r]
                       + sp(hb[r] + ee[r]) * attl[h * 64 + 32 + c0 + r];
            }
        }
        float4 a0v;
#pragma unroll
        for (int h = 0; h < 4; ++h) {
            float v = ph[h];
            v += __shfl_xor(v, 16);
            v += __shfl_xor(v, 32);
            (&a0v.x)[h] = sp(v);
        }
        if (q == 0) {
            *(float4*)&alpha[(size_t)e * 4] = a0v;
#pragma unroll
            for (int h = 0; h < 4; ++h) {
                const float a0 = (&a0v.x)[h];
                bs[h] += a0; bq2[h] += a0 * a0;
            }
        }
    }
#pragma unroll
    for (int h = 0; h < 4; ++h) {
        float v = bs[h], w = bq2[h];
#pragma unroll
        for (int d = 1; d < 64; d <<= 1) { v += __shfl_xor(v, d); w += __shfl_xor(w, d); }
        if (l == 0) { atomicAdd(&bnstat[h], v); atomicAdd(&bnstat[4 + h], w); }
    }
}

// k2: finalize BN scale/shift
__global__ void k2_bn(const float* __restrict__ bnstat, FP gam, FP bet,
                      float* __restrict__ bnsc, int E)
{
    const int t = threadIdx.x;
    if (t < 4) {
        const float inv = 1.f / (float)E;
        const float mu  = bnstat[t] * inv;
        const float var = bnstat[4 + t] * inv - mu * mu;
        const float scl = gam[t] * rsqrtf(var + 1e-5f);
        bnsc[t] = scl;
        bnsc[4 + t] = bet[t] - mu * scl;
    }
}

// k3: alpha1 = sp(scale*alpha0+shift); segment max via uint atomicMax (alpha1>0)
__global__ __launch_bounds__(256) void k3_bnmax(
    float* __restrict__ alpha, const int* __restrict__ eidx,
    unsigned int* __restrict__ mbuf, const float* __restrict__ bnsc, int E)
{
    const int t = blockIdx.x * 256 + threadIdx.x;
    if (t >= 4 * E) return;
    const int e = t >> 2, h = t & 3;
    const float a1 = sp(bnsc[h] * alpha[t] + bnsc[4 + h]);
    alpha[t] = a1;
    atomicMax(&mbuf[eidx[e] * 4 + h], __float_as_uint(a1));
}

// k4: ex = exp(alpha1 - m[row]); segment sum
__global__ __launch_bounds__(256) void k4_exps(
    float* __restrict__ alpha, const int* __restrict__ eidx,
    const float* __restrict__ mbuf, float* __restrict__ sbuf, int E)
{
    const int t = blockIdx.x * 256 + threadIdx.x;
    if (t >= 4 * E) return;
    const int e = t >> 2, h = t & 3;
    const float ex = fexp(alpha[t] - mbuf[eidx[e] * 4 + h]);
    alpha[t] = ex;
    atomicAdd(&sbuf[eidx[e] * 4 + h], ex);
}

// ---------------------------------------------------------------------------
// kmsg2: recompute Ee + Hb from streamed gx/efb; hj = sp(Hb+Ee);
//        out[i] += 0.25*sum_h af_h*hj. Weights in LDS (same fix).
// ---------------------------------------------------------------------------
__global__ __launch_bounds__(256, 2) void kmsg2(
    const short* __restrict__ efb, const short* __restrict__ gx,
    const int* __restrict__ eidx, FP Wg,
    const float* __restrict__ alpha, const float* __restrict__ sbuf,
    float* __restrict__ outacc, int E)
{
    __shared__ __align__(16) short Wl[16][64][8];   // 16 KB
    const int t = threadIdx.x;
    for (int s = t; s < 1024; s += 256) {
        const int f = s >> 6, ll = s & 63;
        FP src = (f < 8) ? Wg : (Wg + 32 * 128);
        bf16x8 fr = load_wfrag(src, 128, 16 * (f & 7), ll);
        *(bf16x8*)&Wl[f][ll][0] = fr;
    }
    __syncthreads();

    const int l = t & 63, q = l >> 4, e15 = l & 15;
    const int wv = blockIdx.x * 4 + (t >> 6), nw = gridDim.x * 4;
    const f32x4 z = {0.f, 0.f, 0.f, 0.f};

    const int nt = E >> 4;
    for (int tt = wv; tt < nt; tt += nw) {
        const int tb = tt * 16;
        const int e = tb + e15;
        const int i = eidx[e];
        const bf16x8 xj = *(const bf16x8*)&gx[(size_t)e * 64 + 32 + 8 * q];
        const bf16x8 xe = *(const bf16x8*)&efb[(size_t)e * 32 + 8 * q];
        const float4 a4 = *(const float4*)&alpha[(size_t)e * 4];
        const float4 s4 = *(const float4*)&sbuf[(size_t)i * 4];
        float af[4];
#pragma unroll
        for (int h = 0; h < 4; ++h)
            af[h] = (&a4.x)[h] * __builtin_amdgcn_rcpf((&s4.x)[h] + 1e-16f);

        float c4[8] = {0,0,0,0,0,0,0,0};
#pragma unroll
        for (int mb = 0; mb < 8; ++mb) {
            const bf16x8 wa = *(const bf16x8*)&Wl[mb][l][0];
            const bf16x8 we = *(const bf16x8*)&Wl[8 + mb][l][0];
            const f32x4 ee = __builtin_amdgcn_mfma_f32_16x16x32_bf16(we, xe, z, 0, 0, 0);
            const f32x4 hb = __builtin_amdgcn_mfma_f32_16x16x32_bf16(wa, xj, z, 0, 0, 0);
            const float a = af[mb >> 1];
            const int s = (mb & 1) * 4;
#pragma unroll
            for (int r = 0; r < 4; ++r)
                c4[s + r] += sp(hb[r] + ee[r]) * a;
        }
#pragma unroll
        for (int s2 = 0; s2 < 2; ++s2)
#pragma unroll
            for (int r = 0; r < 4; ++r)
                atomicAdd(&outacc[(size_t)i * 32 + s2 * 16 + 4 * q + r], 0.25f * c4[s2 * 4 + r]);
    }
}

// kout: out += bias; also write bf16 copy for the edge-MLP gathers
__global__ __launch_bounds__(256) void kout(
    float* __restrict__ outp, FP bias, short* __restrict__ outb, int N)
{
    const int t = blockIdx.x * 256 + threadIdx.x;
    if (t < N * 32) {
        const float v = outp[t] + bias[t & 31];
        outp[t] = v;
        outb[t] = f2bf(v);
    }
}

// ---------------------------------------------------------------------------
// kG2v: edge MLP, W1 and W2 fragments both in LDS.
// ---------------------------------------------------------------------------
__global__ __launch_bounds__(256, 2) void kG2v(
    const short* __restrict__ efb, const int* __restrict__ eidx,
    const short* __restrict__ outb,
    FP W1g, FP W2, FP b1g, FP b2g, float* __restrict__ eout, int E)
{
    __shared__ __align__(16) short W1f[3][8][64][8];   // 24 KB
    __shared__ __align__(16) short W2f[8][64][8];      // 8 KB (frag = kc*2+m2)
    __shared__ float b1l[128];
    __shared__ float b2l[32];
    __shared__ __align__(16) short hs[4][16 * 132];    // 16.9 KB h-bounce
    const int t = threadIdx.x;
    for (int s = t; s < 3 * 8 * 64; s += 256) {
        const int ks = s >> 9, rem = s & 511, mb = rem >> 6, ll = rem & 63;
        const int c = 16 * mb + (ll & 15);
        const int k0 = ks * 32 + 8 * (ll >> 4);
        bf16x8 f;
#pragma unroll
        for (int j = 0; j < 8; ++j) f[j] = f2bf(W1g[(size_t)(k0 + j) * 128 + c]);
        *(bf16x8*)&W1f[ks][mb][ll][0] = f;
    }
    for (int s = t; s < 8 * 64; s += 256) {
        const int f = s >> 6, ll = s & 63;
        const int kc = f >> 1, m2 = f & 1;
        bf16x8 fr = load_wfrag(W2 + 32 * kc * 32, 32, 16 * m2, ll);
        *(bf16x8*)&W2f[f][ll][0] = fr;
    }
    if (t < 128) b1l[t] = b1g[t];
    if (t < 32)  b2l[t] = b2g[t];
    __syncthreads();

    const int l = t & 63, q = l >> 4, e15 = l & 15, wvb = t >> 6;
    short* hw = &hs[wvb][0];
    const f32x4 z = {0.f, 0.f, 0.f, 0.f};

    const int wv = blockIdx.x * 4 + wvb, nw = gridDim.x * 4, nt = E >> 4;
    for (int tt = wv; tt < nt; tt += nw) {
        const int tb = tt * 16;
        const int e = tb + e15;
        const int ri = eidx[e], ci = eidx[E + e];
        bf16x8 xb[3];
        xb[0] = *(const bf16x8*)&outb[(size_t)ri * 32 + 8 * q];
        xb[1] = *(const bf16x8*)&outb[(size_t)ci * 32 + 8 * q];
        xb[2] = *(const bf16x8*)&efb[(size_t)e * 32 + 8 * q];

        f32x4 a1[8] = {z, z, z, z, z, z, z, z};
#pragma unroll
        for (int ks = 0; ks < 3; ++ks)
#pragma unroll
            for (int mb = 0; mb < 8; ++mb) {
                const bf16x8 wfr = *(const bf16x8*)&W1f[ks][mb][l][0];
                a1[mb] = __builtin_amdgcn_mfma_f32_16x16x32_bf16(wfr, xb[ks], a1[mb], 0, 0, 0);
            }
        // silu + bounce into B-frag layout
#pragma unroll
        for (int mb = 0; mb < 8; ++mb) {
            short4 s;
            s.x = f2bf(silu_f(a1[mb][0] + b1l[16 * mb + 4 * q + 0]));
            s.y = f2bf(silu_f(a1[mb][1] + b1l[16 * mb + 4 * q + 1]));
            s.z = f2bf(silu_f(a1[mb][2] + b1l[16 * mb + 4 * q + 2]));
            s.w = f2bf(silu_f(a1[mb][3] + b1l[16 * mb + 4 * q + 3]));
            *(short4*)&hw[e15 * 132 + 16 * mb + 4 * q] = s;
        }
        f32x4 oc0 = z, oc1 = z;
#pragma unroll
        for (int kc = 0; kc < 4; ++kc) {
            const bf16x8 hf = *(const bf16x8*)&hw[e15 * 132 + kc * 32 + 8 * q];
            const bf16x8 w20 = *(const bf16x8*)&W2f[kc * 2][l][0];
            const bf16x8 w21 = *(const bf16x8*)&W2f[kc * 2 + 1][l][0];
            oc0 = __builtin_amdgcn_mfma_f32_16x16x32_bf16(w20, hf, oc0, 0, 0, 0);
            oc1 = __builtin_amdgcn_mfma_f32_16x16x32_bf16(w21, hf, oc1, 0, 0, 0);
        }
        float4 o0, o1;
#pragma unroll
        for (int r = 0; r < 4; ++r) {
            (&o0.x)[r] = silu_f(oc0[r] + b2l[4 * q + r]);
            (&o1.x)[r] = silu_f(oc1[r] + b2l[16 + 4 * q + r]);
        }
        *(float4*)&eout[(size_t)e * 32 + 4 * q] = o0;
        *(float4*)&eout[(size_t)e * 32 + 16 + 4 * q] = o1;
    }
}

extern "C" void kernel_launch(void* const* d_in, const int* in_sizes, int n_in,
                              void* d_out, int out_size, void* d_ws, size_t ws_size,
                              hipStream_t stream)
{
    const float* atom = (const float*)d_in[0];
    const int*   eidx = (const int*)d_in[1];
    const float* efea = (const float*)d_in[2];
    const float* Wg   = (const float*)d_in[6];
    const float* attg = (const float*)d_in[7];
    const float* bias = (const float*)d_in[8];
    const float* gam  = (const float*)d_in[9];
    const float* bet  = (const float*)d_in[10];
    const float* W1g  = (const float*)d_in[11];
    const float* b1g  = (const float*)d_in[12];
    const float* W2g  = (const float*)d_in[13];
    const float* b2g  = (const float*)d_in[14];

    const int N = in_sizes[0] / 32;
    const int E = in_sizes[2] / 32;

    // workspace layout
    float* ws     = (float*)d_ws;
    float* mbuf   = ws;                               // 4N f32
    float* sbuf   = ws + (size_t)4 * N;               // 4N f32
    float* bnstat = ws + (size_t)8 * N;               // 8
    float* bnsc   = bnstat + 8;                       // 8
    short* atomb  = (short*)(ws + (size_t)8 * N + 16);// N*32 bf16
    short* efb    = atomb + (size_t)N * 32;           // E*32 bf16
    short* outb   = efb + (size_t)E * 32;             // N*32 bf16
    short* gx     = outb + (size_t)N * 32;            // E*64 bf16 (xi|xj rows)

    // d_out: [out N*32 f32][eout E*32 f32]; eout region doubles as alpha scratch
    float* outp  = (float*)d_out;
    float* alpha = outp + (size_t)N * 32;             // 4E f32 (dead before eout write)
    float* eout  = outp + (size_t)N * 32;

    hipMemsetAsync(outp, 0, (size_t)N * 32 * sizeof(float), stream);
    hipMemsetAsync(ws, 0, ((size_t)8 * N + 16) * sizeof(float), stream);

    const int n4e = 4 * E;
    kprep<<<1024, 256, 0, stream>>>(atom, efea, atomb, efb, N * 8, E * 8);
    kgath<<<4096, 256, 0, stream>>>(eidx, atomb, gx, E);
    kBc  <<<2048, 256, 0, stream>>>(efb, gx, Wg, attg, alpha, bnstat, E);
    k2_bn<<<1, 64, 0, stream>>>(bnstat, gam, bet, bnsc, E);
    k3_bnmax<<<(n4e + 255) / 256, 256, 0, stream>>>(alpha, eidx, (unsigned int*)mbuf, bnsc, E);
    k4_exps <<<(n4e + 255) / 256, 256, 0, stream>>>(alpha, eidx, mbuf, sbuf, E);
    kmsg2<<<2048, 256, 0, stream>>>(efb, gx, eidx, Wg, alpha, sbuf, outp, E);
    kout <<<(N * 32 + 255) / 256, 256, 0, stream>>>(outp, bias, outb, N);
    kG2v <<<2048, 256, 0, stream>>>(efb, eidx, outb, W1g, W2g, b1g, b2g, eout, E);
}

// Round 10
// 671.615 us; speedup vs baseline: 2.1462x; 2.1416x over previous
//
#include <hip/hip_runtime.h>

typedef __attribute__((ext_vector_type(8))) short bf16x8;
typedef __attribute__((ext_vector_type(4))) float f32x4;

#define FP const float* __restrict__

__device__ __forceinline__ short f2bf(float f) {
    unsigned u = __float_as_uint(f);
    u += 0x7fffu + ((u >> 16) & 1u);
    return (short)(u >> 16);
}
__device__ __forceinline__ float bf2f(short s) {
    return __uint_as_float(((unsigned)(unsigned short)s) << 16);
}
__device__ __forceinline__ float v_exp2(float x) { float r; asm("v_exp_f32 %0, %1" : "=v"(r) : "v"(x)); return r; }
__device__ __forceinline__ float v_log2(float x) { float r; asm("v_log_f32 %0, %1" : "=v"(r) : "v"(x)); return r; }

__device__ __forceinline__ float fexp(float x) { return v_exp2(1.44269504f * x); }
__device__ __forceinline__ float sp(float x) {         // softplus, branch-free
    return fmaxf(x, 0.f) + 0.69314718f * v_log2(1.f + v_exp2(-1.44269504f * fabsf(x)));
}
__device__ __forceinline__ float silu_f(float x) {
    return x * __builtin_amdgcn_rcpf(1.f + v_exp2(-1.44269504f * x));
}

// A-operand = W^T tile: lane l holds W[k, c0+(l&15)], k = 8*(l>>4)+j. W is [32+,ld] f32.
__device__ __forceinline__ bf16x8 load_wfrag(FP w, int ld, int c0, int l) {
    const int c = c0 + (l & 15);
    const int k0 = 8 * (l >> 4);
    bf16x8 f;
#pragma unroll
    for (int j = 0; j < 8; ++j) f[j] = f2bf(w[(k0 + j) * ld + c]);
    return f;
}

// ---------------------------------------------------------------------------
// kprep: bf16-ize atom (N*32) and ef (E*32)
// ---------------------------------------------------------------------------
__global__ __launch_bounds__(256) void kprep(
    FP atom, FP ef, short* __restrict__ atomb, short* __restrict__ efb,
    int nA4, int nE4)
{
    const int stride = gridDim.x * 256;
    for (int t = blockIdx.x * 256 + threadIdx.x; t < nA4 + nE4; t += stride) {
        float4 v;
        short4 s;
        if (t < nA4) {
            v = ((const float4*)atom)[t];
            s.x = f2bf(v.x); s.y = f2bf(v.y); s.z = f2bf(v.z); s.w = f2bf(v.w);
            ((short4*)atomb)[t] = s;
        } else {
            v = ((const float4*)ef)[t - nA4];
            s.x = f2bf(v.x); s.y = f2bf(v.y); s.z = f2bf(v.z); s.w = f2bf(v.w);
            ((short4*)efb)[t - nA4] = s;
        }
    }
}

// ---------------------------------------------------------------------------
// kgath: PURE gather, max TLP (measured fast in R8)
// ---------------------------------------------------------------------------
__global__ __launch_bounds__(256) void kgath(
    const int* __restrict__ eidx, const short* __restrict__ atomb,
    short* __restrict__ gx, int E)
{
    const int stride = gridDim.x * 256;
    const int tot = 8 * E;
    for (int t = blockIdx.x * 256 + threadIdx.x; t < tot; t += stride) {
        const int e = t >> 3, s = (t >> 2) & 1, c = t & 3;
        const int node = eidx[e + (s ? E : 0)];
        const float4 v = *(const float4*)&atomb[(size_t)node * 32 + c * 8];
        *(float4*)&gx[(size_t)t * 8] = v;
    }
}

// ---------------------------------------------------------------------------
// kBc: streaming compute. Weights in LDS. BN stats: wave-shfl reduce ->
// LDS block reduce -> ONE padded per-block partial store (NO same-line atomics;
// R9 post-mortem: 65k atomicAdds to one 32B line = ~0.5ms serialized drain).
// ---------------------------------------------------------------------------
__global__ __launch_bounds__(256, 2) void kBc(
    const short* __restrict__ efb, const short* __restrict__ gx,
    FP Wg, FP attg,
    float* __restrict__ alpha, float* __restrict__ bnpart, int E)
{
    __shared__ float attl[256];
    __shared__ __align__(16) short Wl[16][64][8];   // 16 KB: frag f, lane, 8 bf16
    __shared__ float bnred[4][8];
    const int t = threadIdx.x;
    if (t < 64) ((float4*)attl)[t] = ((const float4*)attg)[t];
    for (int s = t; s < 1024; s += 256) {
        const int f = s >> 6, ll = s & 63;
        FP src = (f < 8) ? Wg : (Wg + 32 * 128);
        bf16x8 fr = load_wfrag(src, 128, 16 * (f & 7), ll);
        *(bf16x8*)&Wl[f][ll][0] = fr;
    }
    __syncthreads();

    const int l = t & 63, q = l >> 4, e15 = l & 15, wvb = t >> 6;
    const int wv = blockIdx.x * 4 + wvb, nw = gridDim.x * 4;
    const f32x4 z = {0.f, 0.f, 0.f, 0.f};
    float bs[4] = {0,0,0,0}, bq2[4] = {0,0,0,0};

    const int nt = E >> 4;
    for (int tt = wv; tt < nt; tt += nw) {
        const int tb = tt * 16;
        const int e = tb + e15;
        const bf16x8 xi = *(const bf16x8*)&gx[(size_t)e * 64 + 8 * q];
        const bf16x8 xj = *(const bf16x8*)&gx[(size_t)e * 64 + 32 + 8 * q];
        const bf16x8 xe = *(const bf16x8*)&efb[(size_t)e * 32 + 8 * q];

        float ph[4] = {0,0,0,0};
#pragma unroll
        for (int mb = 0; mb < 8; ++mb) {
            const bf16x8 wa = *(const bf16x8*)&Wl[mb][l][0];
            const bf16x8 we = *(const bf16x8*)&Wl[8 + mb][l][0];
            const f32x4 ee = __builtin_amdgcn_mfma_f32_16x16x32_bf16(we, xe, z, 0, 0, 0);
            const f32x4 ha = __builtin_amdgcn_mfma_f32_16x16x32_bf16(wa, xi, z, 0, 0, 0);
            const f32x4 hb = __builtin_amdgcn_mfma_f32_16x16x32_bf16(wa, xj, z, 0, 0, 0);
            const int h = mb >> 1;
            const int c0 = (mb & 1) * 16 + 4 * q;
#pragma unroll
            for (int r = 0; r < 4; ++r) {
                ph[h] += sp(ha[r] + ee[r]) * attl[h * 64 + c0 + r]
                       + sp(hb[r] + ee[r]) * attl[h * 64 + 32 + c0 + r];
            }
        }
        float4 a0v;
#pragma unroll
        for (int h = 0; h < 4; ++h) {
            float v = ph[h];
            v += __shfl_xor(v, 16);
            v += __shfl_xor(v, 32);
            (&a0v.x)[h] = sp(v);
        }
        if (q == 0) {
            *(float4*)&alpha[(size_t)e * 4] = a0v;
#pragma unroll
            for (int h = 0; h < 4; ++h) {
                const float a0 = (&a0v.x)[h];
                bs[h] += a0; bq2[h] += a0 * a0;
            }
        }
    }
    // wave reduce -> LDS -> one padded per-block store (no atomics)
#pragma unroll
    for (int h = 0; h < 4; ++h) {
        float v = bs[h], w = bq2[h];
#pragma unroll
        for (int d = 1; d < 64; d <<= 1) { v += __shfl_xor(v, d); w += __shfl_xor(w, d); }
        if (l == 0) { bnred[wvb][h] = v; bnred[wvb][4 + h] = w; }
    }
    __syncthreads();
    if (t < 8) {
        const float s = bnred[0][t] + bnred[1][t] + bnred[2][t] + bnred[3][t];
        bnpart[(size_t)blockIdx.x * 16 + t] = s;   // 64B stride: no line sharing
    }
}

// k2: reduce per-block BN partials, finalize scale/shift
__global__ __launch_bounds__(256) void k2_bn(
    const float* __restrict__ bnpart, int nblk, FP gam, FP bet,
    float* __restrict__ bnsc, int E)
{
    __shared__ float red[256];
    const int t = threadIdx.x;
    const int h = t & 7, c = t >> 3;           // 32 chunks x 8 stats
    float s = 0.f;
    for (int b = c; b < nblk; b += 32) s += bnpart[(size_t)b * 16 + h];
    red[t] = s;
    __syncthreads();
    if (t < 8) {
        float acc = 0.f;
#pragma unroll
        for (int c2 = 0; c2 < 32; ++c2) acc += red[c2 * 8 + t];
        red[t] = acc;
    }
    __syncthreads();
    if (t < 4) {
        const float inv = 1.f / (float)E;
        const float mu  = red[t] * inv;
        const float var = red[4 + t] * inv - mu * mu;
        const float scl = gam[t] * rsqrtf(var + 1e-5f);
        bnsc[t] = scl;
        bnsc[4 + t] = bet[t] - mu * scl;
    }
}

// k3: alpha1 = sp(scale*alpha0+shift); segment max via uint atomicMax (alpha1>0)
__global__ __launch_bounds__(256) void k3_bnmax(
    float* __restrict__ alpha, const int* __restrict__ eidx,
    unsigned int* __restrict__ mbuf, const float* __restrict__ bnsc, int E)
{
    const int t = blockIdx.x * 256 + threadIdx.x;
    if (t >= 4 * E) return;
    const int e = t >> 2, h = t & 3;
    const float a1 = sp(bnsc[h] * alpha[t] + bnsc[4 + h]);
    alpha[t] = a1;
    atomicMax(&mbuf[eidx[e] * 4 + h], __float_as_uint(a1));
}

// k4: ex = exp(alpha1 - m[row]); segment sum
__global__ __launch_bounds__(256) void k4_exps(
    float* __restrict__ alpha, const int* __restrict__ eidx,
    const float* __restrict__ mbuf, float* __restrict__ sbuf, int E)
{
    const int t = blockIdx.x * 256 + threadIdx.x;
    if (t >= 4 * E) return;
    const int e = t >> 2, h = t & 3;
    const float ex = fexp(alpha[t] - mbuf[eidx[e] * 4 + h]);
    alpha[t] = ex;
    atomicAdd(&sbuf[eidx[e] * 4 + h], ex);
}

// ---------------------------------------------------------------------------
// kmsg2: recompute Ee + Hb from streamed gx/efb; hj = sp(Hb+Ee);
//        out[i] += 0.25*sum_h af_h*hj. Weights in LDS.
// ---------------------------------------------------------------------------
__global__ __launch_bounds__(256, 2) void kmsg2(
    const short* __restrict__ efb, const short* __restrict__ gx,
    const int* __restrict__ eidx, FP Wg,
    const float* __restrict__ alpha, const float* __restrict__ sbuf,
    float* __restrict__ outacc, int E)
{
    __shared__ __align__(16) short Wl[16][64][8];   // 16 KB
    const int t = threadIdx.x;
    for (int s = t; s < 1024; s += 256) {
        const int f = s >> 6, ll = s & 63;
        FP src = (f < 8) ? Wg : (Wg + 32 * 128);
        bf16x8 fr = load_wfrag(src, 128, 16 * (f & 7), ll);
        *(bf16x8*)&Wl[f][ll][0] = fr;
    }
    __syncthreads();

    const int l = t & 63, q = l >> 4, e15 = l & 15;
    const int wv = blockIdx.x * 4 + (t >> 6), nw = gridDim.x * 4;
    const f32x4 z = {0.f, 0.f, 0.f, 0.f};

    const int nt = E >> 4;
    for (int tt = wv; tt < nt; tt += nw) {
        const int tb = tt * 16;
        const int e = tb + e15;
        const int i = eidx[e];
        const bf16x8 xj = *(const bf16x8*)&gx[(size_t)e * 64 + 32 + 8 * q];
        const bf16x8 xe = *(const bf16x8*)&efb[(size_t)e * 32 + 8 * q];
        const float4 a4 = *(const float4*)&alpha[(size_t)e * 4];
        const float4 s4 = *(const float4*)&sbuf[(size_t)i * 4];
        float af[4];
#pragma unroll
        for (int h = 0; h < 4; ++h)
            af[h] = (&a4.x)[h] * __builtin_amdgcn_rcpf((&s4.x)[h] + 1e-16f);

        float c4[8] = {0,0,0,0,0,0,0,0};
#pragma unroll
        for (int mb = 0; mb < 8; ++mb) {
            const bf16x8 wa = *(const bf16x8*)&Wl[mb][l][0];
            const bf16x8 we = *(const bf16x8*)&Wl[8 + mb][l][0];
            const f32x4 ee = __builtin_amdgcn_mfma_f32_16x16x32_bf16(we, xe, z, 0, 0, 0);
            const f32x4 hb = __builtin_amdgcn_mfma_f32_16x16x32_bf16(wa, xj, z, 0, 0, 0);
            const float a = af[mb >> 1];
            const int s = (mb & 1) * 4;
#pragma unroll
            for (int r = 0; r < 4; ++r)
                c4[s + r] += sp(hb[r] + ee[r]) * a;
        }
#pragma unroll
        for (int s2 = 0; s2 < 2; ++s2)
#pragma unroll
            for (int r = 0; r < 4; ++r)
                atomicAdd(&outacc[(size_t)i * 32 + s2 * 16 + 4 * q + r], 0.25f * c4[s2 * 4 + r]);
    }
}

// kout: out += bias; also write bf16 copy for the edge-MLP gathers
__global__ __launch_bounds__(256) void kout(
    float* __restrict__ outp, FP bias, short* __restrict__ outb, int N)
{
    const int t = blockIdx.x * 256 + threadIdx.x;
    if (t < N * 32) {
        const float v = outp[t] + bias[t & 31];
        outp[t] = v;
        outb[t] = f2bf(v);
    }
}

// ---------------------------------------------------------------------------
// kG2v: edge MLP, W1 and W2 fragments both in LDS.
// ---------------------------------------------------------------------------
__global__ __launch_bounds__(256, 2) void kG2v(
    const short* __restrict__ efb, const int* __restrict__ eidx,
    const short* __restrict__ outb,
    FP W1g, FP W2, FP b1g, FP b2g, float* __restrict__ eout, int E)
{
    __shared__ __align__(16) short W1f[3][8][64][8];   // 24 KB
    __shared__ __align__(16) short W2f[8][64][8];      // 8 KB (frag = kc*2+m2)
    __shared__ float b1l[128];
    __shared__ float b2l[32];
    __shared__ __align__(16) short hs[4][16 * 132];    // 16.9 KB h-bounce
    const int t = threadIdx.x;
    for (int s = t; s < 3 * 8 * 64; s += 256) {
        const int ks = s >> 9, rem = s & 511, mb = rem >> 6, ll = rem & 63;
        const int c = 16 * mb + (ll & 15);
        const int k0 = ks * 32 + 8 * (ll >> 4);
        bf16x8 f;
#pragma unroll
        for (int j = 0; j < 8; ++j) f[j] = f2bf(W1g[(size_t)(k0 + j) * 128 + c]);
        *(bf16x8*)&W1f[ks][mb][ll][0] = f;
    }
    for (int s = t; s < 8 * 64; s += 256) {
        const int f = s >> 6, ll = s & 63;
        const int kc = f >> 1, m2 = f & 1;
        bf16x8 fr = load_wfrag(W2 + 32 * kc * 32, 32, 16 * m2, ll);
        *(bf16x8*)&W2f[f][ll][0] = fr;
    }
    if (t < 128) b1l[t] = b1g[t];
    if (t < 32)  b2l[t] = b2g[t];
    __syncthreads();

    const int l = t & 63, q = l >> 4, e15 = l & 15, wvb = t >> 6;
    short* hw = &hs[wvb][0];
    const f32x4 z = {0.f, 0.f, 0.f, 0.f};

    const int wv = blockIdx.x * 4 + wvb, nw = gridDim.x * 4, nt = E >> 4;
    for (int tt = wv; tt < nt; tt += nw) {
        const int tb = tt * 16;
        const int e = tb + e15;
        const int ri = eidx[e], ci = eidx[E + e];
        bf16x8 xb[3];
        xb[0] = *(const bf16x8*)&outb[(size_t)ri * 32 + 8 * q];
        xb[1] = *(const bf16x8*)&outb[(size_t)ci * 32 + 8 * q];
        xb[2] = *(const bf16x8*)&efb[(size_t)e * 32 + 8 * q];

        f32x4 a1[8] = {z, z, z, z, z, z, z, z};
#pragma unroll
        for (int ks = 0; ks < 3; ++ks)
#pragma unroll
            for (int mb = 0; mb < 8; ++mb) {
                const bf16x8 wfr = *(const bf16x8*)&W1f[ks][mb][l][0];
                a1[mb] = __builtin_amdgcn_mfma_f32_16x16x32_bf16(wfr, xb[ks], a1[mb], 0, 0, 0);
            }
        // silu + bounce into B-frag layout
#pragma unroll
        for (int mb = 0; mb < 8; ++mb) {
            short4 s;
            s.x = f2bf(silu_f(a1[mb][0] + b1l[16 * mb + 4 * q + 0]));
            s.y = f2bf(silu_f(a1[mb][1] + b1l[16 * mb + 4 * q + 1]));
            s.z = f2bf(silu_f(a1[mb][2] + b1l[16 * mb + 4 * q + 2]));
            s.w = f2bf(silu_f(a1[mb][3] + b1l[16 * mb + 4 * q + 3]));
            *(short4*)&hw[e15 * 132 + 16 * mb + 4 * q] = s;
        }
        f32x4 oc0 = z, oc1 = z;
#pragma unroll
        for (int kc = 0; kc < 4; ++kc) {
            const bf16x8 hf = *(const bf16x8*)&hw[e15 * 132 + kc * 32 + 8 * q];
            const bf16x8 w20 = *(const bf16x8*)&W2f[kc * 2][l][0];
            const bf16x8 w21 = *(const bf16x8*)&W2f[kc * 2 + 1][l][0];
            oc0 = __builtin_amdgcn_mfma_f32_16x16x32_bf16(w20, hf, oc0, 0, 0, 0);
            oc1 = __builtin_amdgcn_mfma_f32_16x16x32_bf16(w21, hf, oc1, 0, 0, 0);
        }
        float4 o0, o1;
#pragma unroll
        for (int r = 0; r < 4; ++r) {
            (&o0.x)[r] = silu_f(oc0[r] + b2l[4 * q + r]);
            (&o1.x)[r] = silu_f(oc1[r] + b2l[16 + 4 * q + r]);
        }
        *(float4*)&eout[(size_t)e * 32 + 4 * q] = o0;
        *(float4*)&eout[(size_t)e * 32 + 16 + 4 * q] = o1;
    }
}

extern "C" void kernel_launch(void* const* d_in, const int* in_sizes, int n_in,
                              void* d_out, int out_size, void* d_ws, size_t ws_size,
                              hipStream_t stream)
{
    const float* atom = (const float*)d_in[0];
    const int*   eidx = (const int*)d_in[1];
    const float* efea = (const float*)d_in[2];
    const float* Wg   = (const float*)d_in[6];
    const float* attg = (const float*)d_in[7];
    const float* bias = (const float*)d_in[8];
    const float* gam  = (const float*)d_in[9];
    const float* bet  = (const float*)d_in[10];
    const float* W1g  = (const float*)d_in[11];
    const float* b1g  = (const float*)d_in[12];
    const float* W2g  = (const float*)d_in[13];
    const float* b2g  = (const float*)d_in[14];

    const int N = in_sizes[0] / 32;
    const int E = in_sizes[2] / 32;
    const int NBLK = 2048;

    // workspace layout
    float* ws     = (float*)d_ws;
    float* mbuf   = ws;                               // 4N f32
    float* sbuf   = ws + (size_t)4 * N;               // 4N f32
    float* bnsc   = ws + (size_t)8 * N + 8;           // 8 f32
    short* atomb  = (short*)(ws + (size_t)8 * N + 16);// N*32 bf16
    short* efb    = atomb + (size_t)N * 32;           // E*32 bf16
    short* outb   = efb + (size_t)E * 32;             // N*32 bf16
    short* gx     = outb + (size_t)N * 32;            // E*64 bf16 (xi|xj rows)
    float* bnpart = (float*)(gx + (size_t)E * 64);    // NBLK*16 f32 (64B/block)

    // d_out: [out N*32 f32][eout E*32 f32]; eout region doubles as alpha scratch
    float* outp  = (float*)d_out;
    float* alpha = outp + (size_t)N * 32;             // 4E f32 (dead before eout write)
    float* eout  = outp + (size_t)N * 32;

    hipMemsetAsync(outp, 0, (size_t)N * 32 * sizeof(float), stream);
    hipMemsetAsync(ws, 0, ((size_t)8 * N + 16) * sizeof(float), stream);

    const int n4e = 4 * E;
    kprep<<<1024, 256, 0, stream>>>(atom, efea, atomb, efb, N * 8, E * 8);
    kgath<<<4096, 256, 0, stream>>>(eidx, atomb, gx, E);
    kBc  <<<NBLK, 256, 0, stream>>>(efb, gx, Wg, attg, alpha, bnpart, E);
    k2_bn<<<1, 256, 0, stream>>>(bnpart, NBLK, gam, bet, bnsc, E);
    k3_bnmax<<<(n4e + 255) / 256, 256, 0, stream>>>(alpha, eidx, (unsigned int*)mbuf, bnsc, E);
    k4_exps <<<(n4e + 255) / 256, 256, 0, stream>>>(alpha, eidx, mbuf, sbuf, E);
    kmsg2<<<2048, 256, 0, stream>>>(efb, gx, eidx, Wg, alpha, sbuf, outp, E);
    kout <<<(N * 32 + 255) / 256, 256, 0, stream>>>(outp, bias, outb, N);
    kG2v <<<2048, 256, 0, stream>>>(efb, eidx, outb, W1g, W2g, b1g, b2g, eout, E);
}

// Round 11
// 531.856 us; speedup vs baseline: 2.7102x; 1.2628x over previous
//
#include <hip/hip_runtime.h>

typedef __attribute__((ext_vector_type(8))) short bf16x8;
typedef __attribute__((ext_vector_type(4))) float f32x4;

#define FP const float* __restrict__

__device__ __forceinline__ short f2bf(float f) {
    unsigned u = __float_as_uint(f);
    u += 0x7fffu + ((u >> 16) & 1u);
    return (short)(u >> 16);
}
__device__ __forceinline__ float bf2f(short s) {
    return __uint_as_float(((unsigned)(unsigned short)s) << 16);
}
__device__ __forceinline__ float v_exp2(float x) { float r; asm("v_exp_f32 %0, %1" : "=v"(r) : "v"(x)); return r; }
__device__ __forceinline__ float v_log2(float x) { float r; asm("v_log_f32 %0, %1" : "=v"(r) : "v"(x)); return r; }

__device__ __forceinline__ float fexp(float x) { return v_exp2(1.44269504f * x); }
__device__ __forceinline__ float sp(float x) {         // softplus, branch-free
    return fmaxf(x, 0.f) + 0.69314718f * v_log2(1.f + v_exp2(-1.44269504f * fabsf(x)));
}
__device__ __forceinline__ float silu_f(float x) {
    return x * __builtin_amdgcn_rcpf(1.f + v_exp2(-1.44269504f * x));
}

// A-operand = W^T tile: lane l holds W[k, c0+(l&15)], k = 8*(l>>4)+j. W is [32+,ld] f32.
__device__ __forceinline__ bf16x8 load_wfrag(FP w, int ld, int c0, int l) {
    const int c = c0 + (l & 15);
    const int k0 = 8 * (l >> 4);
    bf16x8 f;
#pragma unroll
    for (int j = 0; j < 8; ++j) f[j] = f2bf(w[(k0 + j) * ld + c]);
    return f;
}

// ---------------------------------------------------------------------------
// kprep: bf16-ize atom (N*32) and ef (E*32)
// ---------------------------------------------------------------------------
__global__ __launch_bounds__(256) void kprep(
    FP atom, FP ef, short* __restrict__ atomb, short* __restrict__ efb,
    int nA4, int nE4)
{
    const int stride = gridDim.x * 256;
    for (int t = blockIdx.x * 256 + threadIdx.x; t < nA4 + nE4; t += stride) {
        float4 v;
        short4 s;
        if (t < nA4) {
            v = ((const float4*)atom)[t];
            s.x = f2bf(v.x); s.y = f2bf(v.y); s.z = f2bf(v.z); s.w = f2bf(v.w);
            ((short4*)atomb)[t] = s;
        } else {
            v = ((const float4*)ef)[t - nA4];
            s.x = f2bf(v.x); s.y = f2bf(v.y); s.z = f2bf(v.z); s.w = f2bf(v.w);
            ((short4*)efb)[t - nA4] = s;
        }
    }
}

// khist: in-degree histogram over destination (row) nodes
__global__ __launch_bounds__(256) void khist(
    const int* __restrict__ eidx, int* __restrict__ cnt, int E)
{
    const int t = blockIdx.x * 256 + threadIdx.x;
    if (t < E) atomicAdd(&cnt[eidx[t]], 1);
}

// kscan: exclusive prefix sum over cnt[N] -> off[N+1]. One block, 1024 thr.
__global__ __launch_bounds__(1024) void kscan(
    const int* __restrict__ cnt, int* __restrict__ off, int N)
{
    __shared__ int part[1024];
    const int t = threadIdx.x;
    const int chunk = (N + 1023) >> 10;
    int s = 0;
    for (int k = 0; k < chunk; ++k) {
        const int idx = t * chunk + k;
        if (idx < N) s += cnt[idx];
    }
    part[t] = s;
    __syncthreads();
    if (t == 0) {
        int acc = 0;
        for (int k = 0; k < 1024; ++k) { const int c = part[k]; part[k] = acc; acc += c; }
    }
    __syncthreads();
    int run = part[t];
    for (int k = 0; k < chunk; ++k) {
        const int idx = t * chunk + k;
        if (idx < N) { off[idx] = run; run += cnt[idx]; }
    }
    if (t == 1023) off[N] = run;
}

// krank: dst[e] = off[i] + rank within node (atomic rank; order-free sum later)
__global__ __launch_bounds__(256) void krank(
    const int* __restrict__ eidx, const int* __restrict__ off,
    int* __restrict__ cur, int* __restrict__ dst, int E)
{
    const int t = blockIdx.x * 256 + threadIdx.x;
    if (t < E) {
        const int i = eidx[t];
        const int r = atomicAdd(&cur[i], 1);
        dst[t] = off[i] + r;
    }
}

// ---------------------------------------------------------------------------
// kgath: PURE gather, max TLP
// ---------------------------------------------------------------------------
__global__ __launch_bounds__(256) void kgath(
    const int* __restrict__ eidx, const short* __restrict__ atomb,
    short* __restrict__ gx, int E)
{
    const int stride = gridDim.x * 256;
    const int tot = 8 * E;
    for (int t = blockIdx.x * 256 + threadIdx.x; t < tot; t += stride) {
        const int e = t >> 3, s = (t >> 2) & 1, c = t & 3;
        const int node = eidx[e + (s ? E : 0)];
        const float4 v = *(const float4*)&atomb[(size_t)node * 32 + c * 8];
        *(float4*)&gx[(size_t)t * 8] = v;
    }
}

// ---------------------------------------------------------------------------
// kBc: streaming compute. Weights in LDS. BN stats -> padded per-block partials.
// ---------------------------------------------------------------------------
__global__ __launch_bounds__(256, 2) void kBc(
    const short* __restrict__ efb, const short* __restrict__ gx,
    FP Wg, FP attg,
    float* __restrict__ alpha, float* __restrict__ bnpart, int E)
{
    __shared__ float attl[256];
    __shared__ __align__(16) short Wl[16][64][8];   // 16 KB
    __shared__ float bnred[4][8];
    const int t = threadIdx.x;
    if (t < 64) ((float4*)attl)[t] = ((const float4*)attg)[t];
    for (int s = t; s < 1024; s += 256) {
        const int f = s >> 6, ll = s & 63;
        FP src = (f < 8) ? Wg : (Wg + 32 * 128);
        bf16x8 fr = load_wfrag(src, 128, 16 * (f & 7), ll);
        *(bf16x8*)&Wl[f][ll][0] = fr;
    }
    __syncthreads();

    const int l = t & 63, q = l >> 4, e15 = l & 15, wvb = t >> 6;
    const int wv = blockIdx.x * 4 + wvb, nw = gridDim.x * 4;
    const f32x4 z = {0.f, 0.f, 0.f, 0.f};
    float bs[4] = {0,0,0,0}, bq2[4] = {0,0,0,0};

    const int nt = E >> 4;
    for (int tt = wv; tt < nt; tt += nw) {
        const int tb = tt * 16;
        const int e = tb + e15;
        const bf16x8 xi = *(const bf16x8*)&gx[(size_t)e * 64 + 8 * q];
        const bf16x8 xj = *(const bf16x8*)&gx[(size_t)e * 64 + 32 + 8 * q];
        const bf16x8 xe = *(const bf16x8*)&efb[(size_t)e * 32 + 8 * q];

        float ph[4] = {0,0,0,0};
#pragma unroll
        for (int mb = 0; mb < 8; ++mb) {
            const bf16x8 wa = *(const bf16x8*)&Wl[mb][l][0];
            const bf16x8 we = *(const bf16x8*)&Wl[8 + mb][l][0];
            const f32x4 ee = __builtin_amdgcn_mfma_f32_16x16x32_bf16(we, xe, z, 0, 0, 0);
            const f32x4 ha = __builtin_amdgcn_mfma_f32_16x16x32_bf16(wa, xi, z, 0, 0, 0);
            const f32x4 hb = __builtin_amdgcn_mfma_f32_16x16x32_bf16(wa, xj, z, 0, 0, 0);
            const int h = mb >> 1;
            const int c0 = (mb & 1) * 16 + 4 * q;
#pragma unroll
            for (int r = 0; r < 4; ++r) {
                ph[h] += sp(ha[r] + ee[r]) * attl[h * 64 + c0 + r]
                       + sp(hb[r] + ee[r]) * attl[h * 64 + 32 + c0 + r];
            }
        }
        float4 a0v;
#pragma unroll
        for (int h = 0; h < 4; ++h) {
            float v = ph[h];
            v += __shfl_xor(v, 16);
            v += __shfl_xor(v, 32);
            (&a0v.x)[h] = sp(v);
        }
        if (q == 0) {
            *(float4*)&alpha[(size_t)e * 4] = a0v;
#pragma unroll
            for (int h = 0; h < 4; ++h) {
                const float a0 = (&a0v.x)[h];
                bs[h] += a0; bq2[h] += a0 * a0;
            }
        }
    }
#pragma unroll
    for (int h = 0; h < 4; ++h) {
        float v = bs[h], w = bq2[h];
#pragma unroll
        for (int d = 1; d < 64; d <<= 1) { v += __shfl_xor(v, d); w += __shfl_xor(w, d); }
        if (l == 0) { bnred[wvb][h] = v; bnred[wvb][4 + h] = w; }
    }
    __syncthreads();
    if (t < 8) {
        const float s = bnred[0][t] + bnred[1][t] + bnred[2][t] + bnred[3][t];
        bnpart[(size_t)blockIdx.x * 16 + t] = s;
    }
}

// k2: reduce per-block BN partials, finalize scale/shift
__global__ __launch_bounds__(256) void k2_bn(
    const float* __restrict__ bnpart, int nblk, FP gam, FP bet,
    float* __restrict__ bnsc, int E)
{
    __shared__ float red[256];
    const int t = threadIdx.x;
    const int h = t & 7, c = t >> 3;
    float s = 0.f;
    for (int b = c; b < nblk; b += 32) s += bnpart[(size_t)b * 16 + h];
    red[t] = s;
    __syncthreads();
    if (t < 8) {
        float acc = 0.f;
#pragma unroll
        for (int c2 = 0; c2 < 32; ++c2) acc += red[c2 * 8 + t];
        red[t] = acc;
    }
    __syncthreads();
    if (t < 4) {
        const float inv = 1.f / (float)E;
        const float mu  = red[t] * inv;
        const float var = red[4 + t] * inv - mu * mu;
        const float scl = gam[t] * rsqrtf(var + 1e-5f);
        bnsc[t] = scl;
        bnsc[4 + t] = bet[t] - mu * scl;
    }
}

// k34: alpha -> ex = exp(sp(scale*alpha+shift)) in place (no max-subtraction:
// sp output in (0,~5) so exp is safe and softmax ratio is unchanged);
// distributed segment-sum atomics into sbuf.
__global__ __launch_bounds__(256) void k34(
    float* __restrict__ alpha, const int* __restrict__ eidx,
    float* __restrict__ sbuf, const float* __restrict__ bnsc, int E)
{
    const int t = blockIdx.x * 256 + threadIdx.x;
    if (t >= 4 * E) return;
    const int e = t >> 2, h = t & 3;
    const float a1 = sp(bnsc[h] * alpha[t] + bnsc[4 + h]);
    const float ex = fexp(a1);
    alpha[t] = ex;
    atomicAdd(&sbuf[eidx[e] * 4 + h], ex);
}

// ---------------------------------------------------------------------------
// kmsg3: recompute Ee + Hb from streamed gx/efb; hj = sp(Hb+Ee);
// msg[dst[e]] = bf16(sum_h af_h*hj)  -- plain scatter store, NO atomics.
// ---------------------------------------------------------------------------
__global__ __launch_bounds__(256, 2) void kmsg3(
    const short* __restrict__ efb, const short* __restrict__ gx,
    const int* __restrict__ eidx, const int* __restrict__ dst, FP Wg,
    const float* __restrict__ alpha, const float* __restrict__ sbuf,
    short* __restrict__ msg, int E)
{
    __shared__ __align__(16) short Wl[16][64][8];   // 16 KB
    const int t = threadIdx.x;
    for (int s = t; s < 1024; s += 256) {
        const int f = s >> 6, ll = s & 63;
        FP src = (f < 8) ? Wg : (Wg + 32 * 128);
        bf16x8 fr = load_wfrag(src, 128, 16 * (f & 7), ll);
        *(bf16x8*)&Wl[f][ll][0] = fr;
    }
    __syncthreads();

    const int l = t & 63, q = l >> 4, e15 = l & 15;
    const int wv = blockIdx.x * 4 + (t >> 6), nw = gridDim.x * 4;
    const f32x4 z = {0.f, 0.f, 0.f, 0.f};

    const int nt = E >> 4;
    for (int tt = wv; tt < nt; tt += nw) {
        const int tb = tt * 16;
        const int e = tb + e15;
        const int i = eidx[e];
        const int d = dst[e];
        const bf16x8 xj = *(const bf16x8*)&gx[(size_t)e * 64 + 32 + 8 * q];
        const bf16x8 xe = *(const bf16x8*)&efb[(size_t)e * 32 + 8 * q];
        const float4 a4 = *(const float4*)&alpha[(size_t)e * 4];
        const float4 s4 = *(const float4*)&sbuf[(size_t)i * 4];
        float af[4];
#pragma unroll
        for (int h = 0; h < 4; ++h)
            af[h] = (&a4.x)[h] * __builtin_amdgcn_rcpf((&s4.x)[h] + 1e-16f);

        float c4[8] = {0,0,0,0,0,0,0,0};
#pragma unroll
        for (int mb = 0; mb < 8; ++mb) {
            const bf16x8 wa = *(const bf16x8*)&Wl[mb][l][0];
            const bf16x8 we = *(const bf16x8*)&Wl[8 + mb][l][0];
            const f32x4 ee = __builtin_amdgcn_mfma_f32_16x16x32_bf16(we, xe, z, 0, 0, 0);
            const f32x4 hb = __builtin_amdgcn_mfma_f32_16x16x32_bf16(wa, xj, z, 0, 0, 0);
            const float a = af[mb >> 1];
            const int s = (mb & 1) * 4;
#pragma unroll
            for (int r = 0; r < 4; ++r)
                c4[s + r] += sp(hb[r] + ee[r]) * a;
        }
#pragma unroll
        for (int s2 = 0; s2 < 2; ++s2) {
            short4 pk = { f2bf(c4[s2*4+0]), f2bf(c4[s2*4+1]), f2bf(c4[s2*4+2]), f2bf(c4[s2*4+3]) };
            *(short4*)&msg[(size_t)d * 32 + s2 * 16 + 4 * q] = pk;
        }
    }
}

// kred: per node, stream its sorted msg rows, x0.25, +bias -> outp (f32) + outb (bf16)
__global__ __launch_bounds__(256) void kred(
    const int* __restrict__ off, const short* __restrict__ msg, FP bias,
    float* __restrict__ outp, short* __restrict__ outb, int N)
{
    const int lane = threadIdx.x & 31;
    const int sub = threadIdx.x >> 5;
    const float b = bias[lane];
    for (int node = blockIdx.x * 8 + sub; node < N; node += gridDim.x * 8) {
        const int o0 = off[node], o1 = off[node + 1];
        float acc = 0.f;
        for (int p = o0; p < o1; ++p) acc += bf2f(msg[(size_t)p * 32 + lane]);
        const float v = 0.25f * acc + b;
        outp[(size_t)node * 32 + lane] = v;
        outb[(size_t)node * 32 + lane] = f2bf(v);
    }
}

// ---------------------------------------------------------------------------
// kG2v: edge MLP, W1 and W2 fragments both in LDS.
// ---------------------------------------------------------------------------
__global__ __launch_bounds__(256, 2) void kG2v(
    const short* __restrict__ efb, const int* __restrict__ eidx,
    const short* __restrict__ outb,
    FP W1g, FP W2, FP b1g, FP b2g, float* __restrict__ eout, int E)
{
    __shared__ __align__(16) short W1f[3][8][64][8];   // 24 KB
    __shared__ __align__(16) short W2f[8][64][8];      // 8 KB
    __shared__ float b1l[128];
    __shared__ float b2l[32];
    __shared__ __align__(16) short hs[4][16 * 132];    // 16.9 KB
    const int t = threadIdx.x;
    for (int s = t; s < 3 * 8 * 64; s += 256) {
        const int ks = s >> 9, rem = s & 511, mb = rem >> 6, ll = rem & 63;
        const int c = 16 * mb + (ll & 15);
        const int k0 = ks * 32 + 8 * (ll >> 4);
        bf16x8 f;
#pragma unroll
        for (int j = 0; j < 8; ++j) f[j] = f2bf(W1g[(size_t)(k0 + j) * 128 + c]);
        *(bf16x8*)&W1f[ks][mb][ll][0] = f;
    }
    for (int s = t; s < 8 * 64; s += 256) {
        const int f = s >> 6, ll = s & 63;
        const int kc = f >> 1, m2 = f & 1;
        bf16x8 fr = load_wfrag(W2 + 32 * kc * 32, 32, 16 * m2, ll);
        *(bf16x8*)&W2f[f][ll][0] = fr;
    }
    if (t < 128) b1l[t] = b1g[t];
    if (t < 32)  b2l[t] = b2g[t];
    __syncthreads();

    const int l = t & 63, q = l >> 4, e15 = l & 15, wvb = t >> 6;
    short* hw = &hs[wvb][0];
    const f32x4 z = {0.f, 0.f, 0.f, 0.f};

    const int wv = blockIdx.x * 4 + wvb, nw = gridDim.x * 4, nt = E >> 4;
    for (int tt = wv; tt < nt; tt += nw) {
        const int tb = tt * 16;
        const int e = tb + e15;
        const int ri = eidx[e], ci = eidx[E + e];
        bf16x8 xb[3];
        xb[0] = *(const bf16x8*)&outb[(size_t)ri * 32 + 8 * q];
        xb[1] = *(const bf16x8*)&outb[(size_t)ci * 32 + 8 * q];
        xb[2] = *(const bf16x8*)&efb[(size_t)e * 32 + 8 * q];

        f32x4 a1[8] = {z, z, z, z, z, z, z, z};
#pragma unroll
        for (int ks = 0; ks < 3; ++ks)
#pragma unroll
            for (int mb = 0; mb < 8; ++mb) {
                const bf16x8 wfr = *(const bf16x8*)&W1f[ks][mb][l][0];
                a1[mb] = __builtin_amdgcn_mfma_f32_16x16x32_bf16(wfr, xb[ks], a1[mb], 0, 0, 0);
            }
#pragma unroll
        for (int mb = 0; mb < 8; ++mb) {
            short4 s;
            s.x = f2bf(silu_f(a1[mb][0] + b1l[16 * mb + 4 * q + 0]));
            s.y = f2bf(silu_f(a1[mb][1] + b1l[16 * mb + 4 * q + 1]));
            s.z = f2bf(silu_f(a1[mb][2] + b1l[16 * mb + 4 * q + 2]));
            s.w = f2bf(silu_f(a1[mb][3] + b1l[16 * mb + 4 * q + 3]));
            *(short4*)&hw[e15 * 132 + 16 * mb + 4 * q] = s;
        }
        f32x4 oc0 = z, oc1 = z;
#pragma unroll
        for (int kc = 0; kc < 4; ++kc) {
            const bf16x8 hf = *(const bf16x8*)&hw[e15 * 132 + kc * 32 + 8 * q];
            const bf16x8 w20 = *(const bf16x8*)&W2f[kc * 2][l][0];
            const bf16x8 w21 = *(const bf16x8*)&W2f[kc * 2 + 1][l][0];
            oc0 = __builtin_amdgcn_mfma_f32_16x16x32_bf16(w20, hf, oc0, 0, 0, 0);
            oc1 = __builtin_amdgcn_mfma_f32_16x16x32_bf16(w21, hf, oc1, 0, 0, 0);
        }
        float4 o0, o1;
#pragma unroll
        for (int r = 0; r < 4; ++r) {
            (&o0.x)[r] = silu_f(oc0[r] + b2l[4 * q + r]);
            (&o1.x)[r] = silu_f(oc1[r] + b2l[16 + 4 * q + r]);
        }
        *(float4*)&eout[(size_t)e * 32 + 4 * q] = o0;
        *(float4*)&eout[(size_t)e * 32 + 16 + 4 * q] = o1;
    }
}

extern "C" void kernel_launch(void* const* d_in, const int* in_sizes, int n_in,
                              void* d_out, int out_size, void* d_ws, size_t ws_size,
                              hipStream_t stream)
{
    const float* atom = (const float*)d_in[0];
    const int*   eidx = (const int*)d_in[1];
    const float* efea = (const float*)d_in[2];
    const float* Wg   = (const float*)d_in[6];
    const float* attg = (const float*)d_in[7];
    const float* bias = (const float*)d_in[8];
    const float* gam  = (const float*)d_in[9];
    const float* bet  = (const float*)d_in[10];
    const float* W1g  = (const float*)d_in[11];
    const float* b1g  = (const float*)d_in[12];
    const float* W2g  = (const float*)d_in[13];
    const float* b2g  = (const float*)d_in[14];

    const int N = in_sizes[0] / 32;
    const int E = in_sizes[2] / 32;
    const int NBLK = 2048;

    // workspace layout (f32 units, 16B-aligned sections)
    float* ws = (float*)d_ws;
    size_t o = 0;
    float* sbuf   = ws + o;          o += (size_t)4 * N;   // zeroed
    int*   cnt    = (int*)(ws + o);  o += N;               // zeroed
    int*   cur    = (int*)(ws + o);  o += N;               // zeroed
    float* bnsc   = ws + o;          o += 8;
    int*   off    = (int*)(ws + o);  o += (size_t)N + 1;
    o = (o + 3) & ~(size_t)3;
    int*   dst    = (int*)(ws + o);  o += E;
    float* bnpart = ws + o;          o += (size_t)NBLK * 16;
    o = (o + 7) & ~(size_t)7;
    short* atomb  = (short*)(ws + o); o += (size_t)N * 16;   // N*32 bf16
    short* efb    = (short*)(ws + o); o += (size_t)E * 16;   // E*32 bf16
    short* outb   = (short*)(ws + o); o += (size_t)N * 16;   // N*32 bf16
    short* gx     = (short*)(ws + o); o += (size_t)E * 32;   // E*64 bf16

    // d_out: [out N*32 f32][eout E*32 f32]; eout region = alpha + msg scratch
    float* outp  = (float*)d_out;
    float* scratch = outp + (size_t)N * 32;
    float* alpha = scratch;                          // 4E f32
    short* msg   = (short*)(scratch + (size_t)4 * E);// E*32 bf16 (sorted messages)
    float* eout  = scratch;                          // written last by kG2v

    hipMemsetAsync(ws, 0, (size_t)6 * N * sizeof(float), stream);  // sbuf,cnt,cur

    const int n4e = 4 * E;
    kprep<<<1024, 256, 0, stream>>>(atom, efea, atomb, efb, N * 8, E * 8);
    khist<<<(E + 255) / 256, 256, 0, stream>>>(eidx, cnt, E);
    kscan<<<1, 1024, 0, stream>>>(cnt, off, N);
    krank<<<(E + 255) / 256, 256, 0, stream>>>(eidx, off, cur, dst, E);
    kgath<<<4096, 256, 0, stream>>>(eidx, atomb, gx, E);
    kBc  <<<NBLK, 256, 0, stream>>>(efb, gx, Wg, attg, alpha, bnpart, E);
    k2_bn<<<1, 256, 0, stream>>>(bnpart, NBLK, gam, bet, bnsc, E);
    k34  <<<(n4e + 255) / 256, 256, 0, stream>>>(alpha, eidx, sbuf, bnsc, E);
    kmsg3<<<2048, 256, 0, stream>>>(efb, gx, eidx, dst, Wg, alpha, sbuf, msg, E);
    kred <<<4096, 256, 0, stream>>>(off, msg, bias, outp, outb, N);
    kG2v <<<2048, 256, 0, stream>>>(efb, eidx, outb, W1g, W2g, b1g, b2g, eout, E);
}

// Round 12
// 468.156 us; speedup vs baseline: 3.0789x; 1.1361x over previous
//
#include <hip/hip_runtime.h>

typedef __attribute__((ext_vector_type(8))) short bf16x8;
typedef __attribute__((ext_vector_type(4))) float f32x4;

#define FP const float* __restrict__

__device__ __forceinline__ short f2bf(float f) {
    unsigned u = __float_as_uint(f);
    u += 0x7fffu + ((u >> 16) & 1u);
    return (short)(u >> 16);
}
__device__ __forceinline__ float bf2f(short s) {
    return __uint_as_float(((unsigned)(unsigned short)s) << 16);
}
__device__ __forceinline__ float v_exp2(float x) { float r; asm("v_exp_f32 %0, %1" : "=v"(r) : "v"(x)); return r; }
__device__ __forceinline__ float v_log2(float x) { float r; asm("v_log_f32 %0, %1" : "=v"(r) : "v"(x)); return r; }

__device__ __forceinline__ float fexp(float x) { return v_exp2(1.44269504f * x); }
__device__ __forceinline__ float sp(float x) {         // softplus, branch-free
    return fmaxf(x, 0.f) + 0.69314718f * v_log2(1.f + v_exp2(-1.44269504f * fabsf(x)));
}
__device__ __forceinline__ float silu_f(float x) {
    return x * __builtin_amdgcn_rcpf(1.f + v_exp2(-1.44269504f * x));
}

// A-operand = W^T tile: lane l holds W[k, c0+(l&15)], k = 8*(l>>4)+j. W is [32+,ld] f32.
__device__ __forceinline__ bf16x8 load_wfrag(FP w, int ld, int c0, int l) {
    const int c = c0 + (l & 15);
    const int k0 = 8 * (l >> 4);
    bf16x8 f;
#pragma unroll
    for (int j = 0; j < 8; ++j) f[j] = f2bf(w[(k0 + j) * ld + c]);
    return f;
}

// ---------------------------------------------------------------------------
// kprep: bf16-ize atom (N*32) and ef (E*32)
// ---------------------------------------------------------------------------
__global__ __launch_bounds__(256) void kprep(
    FP atom, FP ef, short* __restrict__ atomb, short* __restrict__ efb,
    int nA4, int nE4)
{
    const int stride = gridDim.x * 256;
    for (int t = blockIdx.x * 256 + threadIdx.x; t < nA4 + nE4; t += stride) {
        float4 v;
        short4 s;
        if (t < nA4) {
            v = ((const float4*)atom)[t];
            s.x = f2bf(v.x); s.y = f2bf(v.y); s.z = f2bf(v.z); s.w = f2bf(v.w);
            ((short4*)atomb)[t] = s;
        } else {
            v = ((const float4*)ef)[t - nA4];
            s.x = f2bf(v.x); s.y = f2bf(v.y); s.z = f2bf(v.z); s.w = f2bf(v.w);
            ((short4*)efb)[t - nA4] = s;
        }
    }
}

// khist: in-degree histogram + per-edge rank (atomic return value)
__global__ __launch_bounds__(256) void khist(
    const int* __restrict__ eidx, int* __restrict__ cnt, int* __restrict__ rank, int E)
{
    const int t = blockIdx.x * 256 + threadIdx.x;
    if (t < E) rank[t] = atomicAdd(&cnt[eidx[t]], 1);
}

// kscan: exclusive prefix sum over cnt[N] -> off[N+1]. One block, 1024 thr,
// parallel Hillis-Steele over the 1024 per-thread partials.
__global__ __launch_bounds__(1024) void kscan(
    const int* __restrict__ cnt, int* __restrict__ off, int N)
{
    __shared__ int pa[1024], pb[1024];
    const int t = threadIdx.x;
    const int chunk = (N + 1023) >> 10;
    const int i0 = t * chunk;
    int s = 0;
    for (int k = 0; k < chunk; ++k) {
        const int idx = i0 + k;
        if (idx < N) s += cnt[idx];
    }
    pa[t] = s;
    __syncthreads();
    int* src = pa; int* dstp = pb;
#pragma unroll
    for (int d = 1; d < 1024; d <<= 1) {
        int v = src[t];
        if (t >= d) v += src[t - d];
        dstp[t] = v;
        __syncthreads();
        int* tmp = src; src = dstp; dstp = tmp;
    }
    int run = (t == 0) ? 0 : src[t - 1];
    for (int k = 0; k < chunk; ++k) {
        const int idx = i0 + k;
        if (idx < N) { off[idx] = run; run += cnt[idx]; }
    }
    if (t == 1023) off[N] = run;
}

// ---------------------------------------------------------------------------
// kBc: inline-gather compute (atomb is 3.2MB -> L2 resident; R7 measured the
// inline-gather loop ~= streamed loop). Weights in LDS. BN stats -> padded
// per-block partial stores.
// ---------------------------------------------------------------------------
__global__ __launch_bounds__(256, 2) void kBc(
    const short* __restrict__ efb, const int* __restrict__ eidx,
    const short* __restrict__ atomb, FP Wg, FP attg,
    float* __restrict__ alpha, float* __restrict__ bnpart, int E)
{
    __shared__ float attl[256];
    __shared__ __align__(16) short Wl[16][64][8];   // 16 KB
    __shared__ float bnred[4][8];
    const int t = threadIdx.x;
    if (t < 64) ((float4*)attl)[t] = ((const float4*)attg)[t];
    for (int s = t; s < 1024; s += 256) {
        const int f = s >> 6, ll = s & 63;
        FP src = (f < 8) ? Wg : (Wg + 32 * 128);
        bf16x8 fr = load_wfrag(src, 128, 16 * (f & 7), ll);
        *(bf16x8*)&Wl[f][ll][0] = fr;
    }
    __syncthreads();

    const int l = t & 63, q = l >> 4, e15 = l & 15, wvb = t >> 6;
    const int wv = blockIdx.x * 4 + wvb, nw = gridDim.x * 4;
    const f32x4 z = {0.f, 0.f, 0.f, 0.f};
    float bs[4] = {0,0,0,0}, bq2[4] = {0,0,0,0};

    const int nt = E >> 4;
    for (int tt = wv; tt < nt; tt += nw) {
        const int tb = tt * 16;
        const int e = tb + e15;
        const int i = eidx[e], j = eidx[E + e];
        const bf16x8 xi = *(const bf16x8*)&atomb[(size_t)i * 32 + 8 * q];
        const bf16x8 xj = *(const bf16x8*)&atomb[(size_t)j * 32 + 8 * q];
        const bf16x8 xe = *(const bf16x8*)&efb[(size_t)e * 32 + 8 * q];

        float ph[4] = {0,0,0,0};
#pragma unroll
        for (int mb = 0; mb < 8; ++mb) {
            const bf16x8 wa = *(const bf16x8*)&Wl[mb][l][0];
            const bf16x8 we = *(const bf16x8*)&Wl[8 + mb][l][0];
            const f32x4 ee = __builtin_amdgcn_mfma_f32_16x16x32_bf16(we, xe, z, 0, 0, 0);
            const f32x4 ha = __builtin_amdgcn_mfma_f32_16x16x32_bf16(wa, xi, z, 0, 0, 0);
            const f32x4 hb = __builtin_amdgcn_mfma_f32_16x16x32_bf16(wa, xj, z, 0, 0, 0);
            const int h = mb >> 1;
            const int c0 = (mb & 1) * 16 + 4 * q;
#pragma unroll
            for (int r = 0; r < 4; ++r) {
                ph[h] += sp(ha[r] + ee[r]) * attl[h * 64 + c0 + r]
                       + sp(hb[r] + ee[r]) * attl[h * 64 + 32 + c0 + r];
            }
        }
        float4 a0v;
#pragma unroll
        for (int h = 0; h < 4; ++h) {
            float v = ph[h];
            v += __shfl_xor(v, 16);
            v += __shfl_xor(v, 32);
            (&a0v.x)[h] = sp(v);
        }
        if (q == 0) {
            *(float4*)&alpha[(size_t)e * 4] = a0v;
#pragma unroll
            for (int h = 0; h < 4; ++h) {
                const float a0 = (&a0v.x)[h];
                bs[h] += a0; bq2[h] += a0 * a0;
            }
        }
    }
#pragma unroll
    for (int h = 0; h < 4; ++h) {
        float v = bs[h], w = bq2[h];
#pragma unroll
        for (int d = 1; d < 64; d <<= 1) { v += __shfl_xor(v, d); w += __shfl_xor(w, d); }
        if (l == 0) { bnred[wvb][h] = v; bnred[wvb][4 + h] = w; }
    }
    __syncthreads();
    if (t < 8) {
        const float s = bnred[0][t] + bnred[1][t] + bnred[2][t] + bnred[3][t];
        bnpart[(size_t)blockIdx.x * 16 + t] = s;
    }
}

// k2: reduce per-block BN partials, finalize scale/shift
__global__ __launch_bounds__(256) void k2_bn(
    const float* __restrict__ bnpart, int nblk, FP gam, FP bet,
    float* __restrict__ bnsc, int E)
{
    __shared__ float red[256];
    const int t = threadIdx.x;
    const int h = t & 7, c = t >> 3;
    float s = 0.f;
    for (int b = c; b < nblk; b += 32) s += bnpart[(size_t)b * 16 + h];
    red[t] = s;
    __syncthreads();
    if (t < 8) {
        float acc = 0.f;
#pragma unroll
        for (int c2 = 0; c2 < 32; ++c2) acc += red[c2 * 8 + t];
        red[t] = acc;
    }
    __syncthreads();
    if (t < 4) {
        const float inv = 1.f / (float)E;
        const float mu  = red[t] * inv;
        const float var = red[4 + t] * inv - mu * mu;
        const float scl = gam[t] * rsqrtf(var + 1e-5f);
        bnsc[t] = scl;
        bnsc[4 + t] = bet[t] - mu * scl;
    }
}

// k34: alpha -> ex = exp(sp(scale*alpha+shift)) in place; distributed seg-sum.
__global__ __launch_bounds__(256) void k34(
    float* __restrict__ alpha, const int* __restrict__ eidx,
    float* __restrict__ sbuf, const float* __restrict__ bnsc, int E)
{
    const int t = blockIdx.x * 256 + threadIdx.x;
    if (t >= 4 * E) return;
    const int e = t >> 2, h = t & 3;
    const float a1 = sp(bnsc[h] * alpha[t] + bnsc[4 + h]);
    const float ex = fexp(a1);
    alpha[t] = ex;
    atomicAdd(&sbuf[eidx[e] * 4 + h], ex);
}

// ---------------------------------------------------------------------------
// kmsg3: inline-gather xj; recompute Ee + Hb; hj = sp(Hb+Ee);
// msg[off[i]+rank[e]] = bf16(sum_h af_h*hj) -- plain scatter store, NO atomics.
// ---------------------------------------------------------------------------
__global__ __launch_bounds__(256, 2) void kmsg3(
    const short* __restrict__ efb, const int* __restrict__ eidx,
    const short* __restrict__ atomb, const int* __restrict__ off,
    const int* __restrict__ rank, FP Wg,
    const float* __restrict__ alpha, const float* __restrict__ sbuf,
    short* __restrict__ msg, int E)
{
    __shared__ __align__(16) short Wl[16][64][8];   // 16 KB
    const int t = threadIdx.x;
    for (int s = t; s < 1024; s += 256) {
        const int f = s >> 6, ll = s & 63;
        FP src = (f < 8) ? Wg : (Wg + 32 * 128);
        bf16x8 fr = load_wfrag(src, 128, 16 * (f & 7), ll);
        *(bf16x8*)&Wl[f][ll][0] = fr;
    }
    __syncthreads();

    const int l = t & 63, q = l >> 4, e15 = l & 15;
    const int wv = blockIdx.x * 4 + (t >> 6), nw = gridDim.x * 4;
    const f32x4 z = {0.f, 0.f, 0.f, 0.f};

    const int nt = E >> 4;
    for (int tt = wv; tt < nt; tt += nw) {
        const int tb = tt * 16;
        const int e = tb + e15;
        const int i = eidx[e], j = eidx[E + e];
        const int d = off[i] + rank[e];
        const bf16x8 xj = *(const bf16x8*)&atomb[(size_t)j * 32 + 8 * q];
        const bf16x8 xe = *(const bf16x8*)&efb[(size_t)e * 32 + 8 * q];
        const float4 a4 = *(const float4*)&alpha[(size_t)e * 4];
        const float4 s4 = *(const float4*)&sbuf[(size_t)i * 4];
        float af[4];
#pragma unroll
        for (int h = 0; h < 4; ++h)
            af[h] = (&a4.x)[h] * __builtin_amdgcn_rcpf((&s4.x)[h] + 1e-16f);

        float c4[8] = {0,0,0,0,0,0,0,0};
#pragma unroll
        for (int mb = 0; mb < 8; ++mb) {
            const bf16x8 wa = *(const bf16x8*)&Wl[mb][l][0];
            const bf16x8 we = *(const bf16x8*)&Wl[8 + mb][l][0];
            const f32x4 ee = __builtin_amdgcn_mfma_f32_16x16x32_bf16(we, xe, z, 0, 0, 0);
            const f32x4 hb = __builtin_amdgcn_mfma_f32_16x16x32_bf16(wa, xj, z, 0, 0, 0);
            const float a = af[mb >> 1];
            const int s = (mb & 1) * 4;
#pragma unroll
            for (int r = 0; r < 4; ++r)
                c4[s + r] += sp(hb[r] + ee[r]) * a;
        }
#pragma unroll
        for (int s2 = 0; s2 < 2; ++s2) {
            short4 pk = { f2bf(c4[s2*4+0]), f2bf(c4[s2*4+1]), f2bf(c4[s2*4+2]), f2bf(c4[s2*4+3]) };
            *(short4*)&msg[(size_t)d * 32 + s2 * 16 + 4 * q] = pk;
        }
    }
}

// kred: per node, stream its sorted msg rows, x0.25, +bias -> outp (f32) + outb (bf16)
__global__ __launch_bounds__(256) void kred(
    const int* __restrict__ off, const short* __restrict__ msg, FP bias,
    float* __restrict__ outp, short* __restrict__ outb, int N)
{
    const int lane = threadIdx.x & 31;
    const int sub = threadIdx.x >> 5;
    const float b = bias[lane];
    for (int node = blockIdx.x * 8 + sub; node < N; node += gridDim.x * 8) {
        const int o0 = off[node], o1 = off[node + 1];
        float acc = 0.f;
        for (int p = o0; p < o1; ++p) acc += bf2f(msg[(size_t)p * 32 + lane]);
        const float v = 0.25f * acc + b;
        outp[(size_t)node * 32 + lane] = v;
        outb[(size_t)node * 32 + lane] = f2bf(v);
    }
}

// ---------------------------------------------------------------------------
// kG2v: edge MLP, W1 and W2 fragments both in LDS.
// ---------------------------------------------------------------------------
__global__ __launch_bounds__(256, 2) void kG2v(
    const short* __restrict__ efb, const int* __restrict__ eidx,
    const short* __restrict__ outb,
    FP W1g, FP W2, FP b1g, FP b2g, float* __restrict__ eout, int E)
{
    __shared__ __align__(16) short W1f[3][8][64][8];   // 24 KB
    __shared__ __align__(16) short W2f[8][64][8];      // 8 KB
    __shared__ float b1l[128];
    __shared__ float b2l[32];
    __shared__ __align__(16) short hs[4][16 * 132];    // 16.9 KB
    const int t = threadIdx.x;
    for (int s = t; s < 3 * 8 * 64; s += 256) {
        const int ks = s >> 9, rem = s & 511, mb = rem >> 6, ll = rem & 63;
        const int c = 16 * mb + (ll & 15);
        const int k0 = ks * 32 + 8 * (ll >> 4);
        bf16x8 f;
#pragma unroll
        for (int j = 0; j < 8; ++j) f[j] = f2bf(W1g[(size_t)(k0 + j) * 128 + c]);
        *(bf16x8*)&W1f[ks][mb][ll][0] = f;
    }
    for (int s = t; s < 8 * 64; s += 256) {
        const int f = s >> 6, ll = s & 63;
        const int kc = f >> 1, m2 = f & 1;
        bf16x8 fr = load_wfrag(W2 + 32 * kc * 32, 32, 16 * m2, ll);
        *(bf16x8*)&W2f[f][ll][0] = fr;
    }
    if (t < 128) b1l[t] = b1g[t];
    if (t < 32)  b2l[t] = b2g[t];
    __syncthreads();

    const int l = t & 63, q = l >> 4, e15 = l & 15, wvb = t >> 6;
    short* hw = &hs[wvb][0];
    const f32x4 z = {0.f, 0.f, 0.f, 0.f};

    const int wv = blockIdx.x * 4 + wvb, nw = gridDim.x * 4, nt = E >> 4;
    for (int tt = wv; tt < nt; tt += nw) {
        const int tb = tt * 16;
        const int e = tb + e15;
        const int ri = eidx[e], ci = eidx[E + e];
        bf16x8 xb[3];
        xb[0] = *(const bf16x8*)&outb[(size_t)ri * 32 + 8 * q];
        xb[1] = *(const bf16x8*)&outb[(size_t)ci * 32 + 8 * q];
        xb[2] = *(const bf16x8*)&efb[(size_t)e * 32 + 8 * q];

        f32x4 a1[8] = {z, z, z, z, z, z, z, z};
#pragma unroll
        for (int ks = 0; ks < 3; ++ks)
#pragma unroll
            for (int mb = 0; mb < 8; ++mb) {
                const bf16x8 wfr = *(const bf16x8*)&W1f[ks][mb][l][0];
                a1[mb] = __builtin_amdgcn_mfma_f32_16x16x32_bf16(wfr, xb[ks], a1[mb], 0, 0, 0);
            }
#pragma unroll
        for (int mb = 0; mb < 8; ++mb) {
            short4 s;
            s.x = f2bf(silu_f(a1[mb][0] + b1l[16 * mb + 4 * q + 0]));
            s.y = f2bf(silu_f(a1[mb][1] + b1l[16 * mb + 4 * q + 1]));
            s.z = f2bf(silu_f(a1[mb][2] + b1l[16 * mb + 4 * q + 2]));
            s.w = f2bf(silu_f(a1[mb][3] + b1l[16 * mb + 4 * q + 3]));
            *(short4*)&hw[e15 * 132 + 16 * mb + 4 * q] = s;
        }
        f32x4 oc0 = z, oc1 = z;
#pragma unroll
        for (int kc = 0; kc < 4; ++kc) {
            const bf16x8 hf = *(const bf16x8*)&hw[e15 * 132 + kc * 32 + 8 * q];
            const bf16x8 w20 = *(const bf16x8*)&W2f[kc * 2][l][0];
            const bf16x8 w21 = *(const bf16x8*)&W2f[kc * 2 + 1][l][0];
            oc0 = __builtin_amdgcn_mfma_f32_16x16x32_bf16(w20, hf, oc0, 0, 0, 0);
            oc1 = __builtin_amdgcn_mfma_f32_16x16x32_bf16(w21, hf, oc1, 0, 0, 0);
        }
        float4 o0, o1;
#pragma unroll
        for (int r = 0; r < 4; ++r) {
            (&o0.x)[r] = silu_f(oc0[r] + b2l[4 * q + r]);
            (&o1.x)[r] = silu_f(oc1[r] + b2l[16 + 4 * q + r]);
        }
        *(float4*)&eout[(size_t)e * 32 + 4 * q] = o0;
        *(float4*)&eout[(size_t)e * 32 + 16 + 4 * q] = o1;
    }
}

extern "C" void kernel_launch(void* const* d_in, const int* in_sizes, int n_in,
                              void* d_out, int out_size, void* d_ws, size_t ws_size,
                              hipStream_t stream)
{
    const float* atom = (const float*)d_in[0];
    const int*   eidx = (const int*)d_in[1];
    const float* efea = (const float*)d_in[2];
    const float* Wg   = (const float*)d_in[6];
    const float* attg = (const float*)d_in[7];
    const float* bias = (const float*)d_in[8];
    const float* gam  = (const float*)d_in[9];
    const float* bet  = (const float*)d_in[10];
    const float* W1g  = (const float*)d_in[11];
    const float* b1g  = (const float*)d_in[12];
    const float* W2g  = (const float*)d_in[13];
    const float* b2g  = (const float*)d_in[14];

    const int N = in_sizes[0] / 32;
    const int E = in_sizes[2] / 32;
    const int NBLK = 2048;

    // workspace layout (f32 units, 16B-aligned sections)
    float* ws = (float*)d_ws;
    size_t o = 0;
    float* sbuf   = ws + o;          o += (size_t)4 * N;   // zeroed
    int*   cnt    = (int*)(ws + o);  o += N;               // zeroed
    float* bnsc   = ws + o;          o += 8;
    int*   off    = (int*)(ws + o);  o += (size_t)N + 1;
    o = (o + 3) & ~(size_t)3;
    int*   rank   = (int*)(ws + o);  o += E;
    float* bnpart = ws + o;          o += (size_t)NBLK * 16;
    o = (o + 7) & ~(size_t)7;
    short* atomb  = (short*)(ws + o); o += (size_t)N * 16;   // N*32 bf16
    short* efb    = (short*)(ws + o); o += (size_t)E * 16;   // E*32 bf16
    short* outb   = (short*)(ws + o); o += (size_t)N * 16;   // N*32 bf16

    // d_out: [out N*32 f32][eout E*32 f32]; eout region = alpha + msg scratch
    float* outp  = (float*)d_out;
    float* scratch = outp + (size_t)N * 32;
    float* alpha = scratch;                          // 4E f32
    short* msg   = (short*)(scratch + (size_t)4 * E);// E*32 bf16 (sorted messages)
    float* eout  = scratch;                          // written last by kG2v

    hipMemsetAsync(ws, 0, (size_t)5 * N * sizeof(float), stream);  // sbuf,cnt

    const int n4e = 4 * E;
    kprep<<<1024, 256, 0, stream>>>(atom, efea, atomb, efb, N * 8, E * 8);
    khist<<<(E + 255) / 256, 256, 0, stream>>>(eidx, cnt, rank, E);
    kscan<<<1, 1024, 0, stream>>>(cnt, off, N);
    kBc  <<<NBLK, 256, 0, stream>>>(efb, eidx, atomb, Wg, attg, alpha, bnpart, E);
    k2_bn<<<1, 256, 0, stream>>>(bnpart, NBLK, gam, bet, bnsc, E);
    k34  <<<(n4e + 255) / 256, 256, 0, stream>>>(alpha, eidx, sbuf, bnsc, E);
    kmsg3<<<2048, 256, 0, stream>>>(efb, eidx, atomb, off, rank, Wg, alpha, sbuf, msg, E);
    kred <<<4096, 256, 0, stream>>>(off, msg, bias, outp, outb, N);
    kG2v <<<2048, 256, 0, stream>>>(efb, eidx, outb, W1g, W2g, b1g, b2g, eout, E);
}